// Round 8
// baseline (420.038 us; speedup 1.0000x reference)
//
#include <hip/hip_runtime.h>
#include <math.h>

// Problem constants (fixed by setup_inputs)
constexpr int BB = 8;
constexpr int NN = 16384;
constexpr int SS = 2048;
constexpr int D2 = 256;
constexpr int H1 = 256;
constexpr int H2 = 128;
constexpr int MM = BB * NN;   // 131072 rows
constexpr int LDB = 40;       // LDS leading dim (bf16 elems): 80 B, 16B-aligned

typedef __attribute__((ext_vector_type(8))) short short8;    // bf16x8 frag (4 VGPRs)
typedef __attribute__((ext_vector_type(16))) float f32x16;   // 32x32 accumulator

__device__ __forceinline__ unsigned short f2b(float f) {     // fp32 -> bf16 RNE
    union { float f; unsigned u; } v; v.f = f;
    unsigned r = v.u + 0x7FFFu + ((v.u >> 16) & 1u);
    return (unsigned short)(r >> 16);
}
__device__ __forceinline__ unsigned pk2(float lo, float hi) {
    return (unsigned)f2b(lo) | ((unsigned)f2b(hi) << 16);
}
__device__ __forceinline__ float b2f_lo(unsigned p) { return __uint_as_float(p << 16); }
__device__ __forceinline__ float b2f_hi(unsigned p) { return __uint_as_float(p & 0xFFFF0000u); }

__device__ __forceinline__ unsigned umed3(unsigned a, unsigned b, unsigned c) {
    unsigned d; asm("v_med3_u32 %0, %1, %2, %3" : "=v"(d) : "v"(a), "v"(b), "v"(c)); return d;
}

// ---------------------------------------------------------------- init
__global__ void k_init(float* __restrict__ st1, float* __restrict__ st2,
                       float* __restrict__ psum, int* __restrict__ pmax) {
    int t = threadIdx.x;
    if (t < 512) st1[t] = 0.f;
    if (t < 256) st2[t] = 0.f;
    if (t < 1024) { psum[t] = 0.f; pmax[t] = 0; }
}

// ---------------------------------------------------------------- weight fp32->bf16 prep
__global__ void k_wprep(const float* __restrict__ w1, const float* __restrict__ w2,
                        unsigned short* __restrict__ w1b, unsigned short* __restrict__ w2b) {
    int i = blockIdx.x * 256 + threadIdx.x;
    if (i < H1 * 384) w1b[i] = f2b(w1[i]);
    if (i < H2 * 256) w2b[i] = f2b(w2[i]);
}

// ---------------------------------------------------------------- xyz2 -> float4 pack (for scalar loads)
__global__ void k_xyzprep(const float* __restrict__ xyz2, float4* __restrict__ xyz2p) {
    int i = blockIdx.x * 256 + threadIdx.x;   // 0 .. BB*SS-1
    if (i < BB * SS) {
        xyz2p[i] = make_float4(xyz2[i * 3], xyz2[i * 3 + 1], xyz2[i * 3 + 2], 0.f);
    }
}

// ---------------------------------------------------------------- 3-NN
// Wave-uniform float4 candidate stream; top-4 insert via {min, med3, med3, med3}.
__global__ __launch_bounds__(256) void k_knn(const float* __restrict__ xyz1,
                                             const float4* __restrict__ xyz2p,
                                             int* __restrict__ idx,
                                             float* __restrict__ wgt) {
    __shared__ unsigned cand[64][16];             // 4 KB: [query][chunk*4+t]
    const int b = blockIdx.y;
    const int tid = threadIdx.x;
    const int ql = tid & 63;                      // query-local
    const int n = blockIdx.x * 64 + ql;

    const float* q = xyz1 + ((size_t)b * NN + n) * 3;
    const float qx = q[0], qy = q[1], qz = q[2];

    // wave-uniform chunk base -> scalar loads through K$
    const int chunk = __builtin_amdgcn_readfirstlane(tid >> 6);   // 0..3
    const float4* cp = xyz2p + ((size_t)b << 11) + (chunk << 9);

    unsigned k0 = 0xFFFFFFFFu, k1 = 0xFFFFFFFFu, k2 = 0xFFFFFFFFu, k3 = 0xFFFFFFFFu;
#pragma unroll 4
    for (int j = 0; j < 512; ++j) {
        const float4 p = cp[j];
        const float dx = qx - p.x;
        const float dy = qy - p.y;
        const float dz = qz - p.z;
        const float d = fmaf(dx, dx, fmaf(dy, dy, dz * dz));
        const unsigned key = (__float_as_uint(d) & 0xFFFFFE00u) | (unsigned)j;
        // sorted top-4 insert: {min, med3, med3, med3} (4 independent ops)
        const unsigned n0 = min(k0, key);
        const unsigned n1 = umed3(k0, k1, key);
        const unsigned n2 = umed3(k1, k2, key);
        const unsigned n3 = umed3(k2, k3, key);
        k0 = n0; k1 = n1; k2 = n2; k3 = n3;
    }
    unsigned* cq = cand[ql] + chunk * 4;
    cq[0] = k0; cq[1] = k1; cq[2] = k2; cq[3] = k3;
    __syncthreads();

    if (tid < 64) {
        const double qxd = (double)qx, qyd = (double)qy, qzd = (double)qz;
        double t0 = 1e300, t1 = 1e300, t2 = 1e300;
        int i0 = 0, i1 = 0, i2 = 0;
#pragma unroll
        for (int c = 0; c < 16; ++c) {
            const int s = ((c >> 2) << 9) + (int)(cand[tid][c] & 0x1FFu);
            const float4 p = xyz2p[((size_t)b << 11) + s];
            const double dx = qxd - (double)p.x;
            const double dy = qyd - (double)p.y;
            const double dz = qzd - (double)p.z;
            const double d = fma(dx, dx, fma(dy, dy, dz * dz));
            if (d < t2) {
                if (d < t0)      { t2 = t1; i2 = i1; t1 = t0; i1 = i0; t0 = d; i0 = s; }
                else if (d < t1) { t2 = t1; i2 = i1; t1 = d; i1 = s; }
                else             { t2 = d; i2 = s; }
            }
        }
        const double r0 = 1.0 / (t0 + 1e-8);
        const double r1 = 1.0 / (t1 + 1e-8);
        const double r2 = 1.0 / (t2 + 1e-8);
        const double inv = 1.0 / (r0 + r1 + r2);
        const size_t o = ((size_t)b * NN + n) * 3;
        idx[o + 0] = i0; idx[o + 1] = i1; idx[o + 2] = i2;
        wgt[o + 0] = (float)(r0 * inv);
        wgt[o + 1] = (float)(r1 * inv);
        wgt[o + 2] = (float)(r2 * inv);
    }
}

// ---------------------------------------------------------------- Z-prep: Z = p2 x W1tail^T
// XCD-aligned: block d -> XCD d%8 (HW round-robin), batch = d&7, so batch b's
// Z slice is produced (and likely cached) on XCD b.
__global__ __launch_bounds__(256) void k_zprep(const float* __restrict__ p2,
                                               const unsigned short* __restrict__ w1b,
                                               float* __restrict__ Z) {
    __shared__ __align__(16) unsigned short As[64 * LDB];    // 5 KB
    __shared__ __align__(16) unsigned short Bs[256 * LDB];   // 20 KB
    const int tid = threadIdx.x;
    const int bid = blockIdx.x;                   // 256 = 8 batches x 32
    const int s0 = ((bid & 7) << 11) + ((bid >> 3) << 6);
    const int wave = tid >> 6, lane = tid & 63;
    const int ln = lane & 31, hk = lane >> 5;
    const int wn = wave << 6;                 // wave-tile 64 rows x 64 cols
    const int r = tid >> 2, q = tid & 3;

    f32x16 acc[2][2];
#pragma unroll
    for (int mt = 0; mt < 2; ++mt)
#pragma unroll
        for (int nt = 0; nt < 2; ++nt)
#pragma unroll
            for (int e = 0; e < 16; ++e) acc[mt][nt][e] = 0.f;

    float4 ra[2];
    uint4 rb[4];
    auto prefetch = [&](int kc) {
        const unsigned short* bsrc = w1b + (size_t)tid * 384 + 128 + kc * 32;
        rb[0] = *(const uint4*)(bsrc);
        rb[1] = *(const uint4*)(bsrc + 8);
        rb[2] = *(const uint4*)(bsrc + 16);
        rb[3] = *(const uint4*)(bsrc + 24);
        const float* asrc = p2 + (((size_t)(s0 + r)) << 8) + kc * 32 + q * 8;
        ra[0] = *(const float4*)(asrc);
        ra[1] = *(const float4*)(asrc + 4);
    };

    prefetch(0);

    for (int kc = 0; kc < 8; ++kc) {
        const uint4 pa = make_uint4(pk2(ra[0].x, ra[0].y), pk2(ra[0].z, ra[0].w),
                                    pk2(ra[1].x, ra[1].y), pk2(ra[1].z, ra[1].w));
        const uint4 b0 = rb[0], b1 = rb[1], b2 = rb[2], b3 = rb[3];

        __syncthreads();
        *(uint4*)&As[r * LDB + q * 8] = pa;
        *(uint4*)&Bs[tid * LDB + 0]  = b0;
        *(uint4*)&Bs[tid * LDB + 8]  = b1;
        *(uint4*)&Bs[tid * LDB + 16] = b2;
        *(uint4*)&Bs[tid * LDB + 24] = b3;
        __syncthreads();

        if (kc < 7) prefetch(kc + 1);

        short8 af[2][2], bfv[2][2];
#pragma unroll
        for (int mt = 0; mt < 2; ++mt)
#pragma unroll
            for (int ks = 0; ks < 2; ++ks)
                af[mt][ks] = *(const short8*)&As[(mt * 32 + ln) * LDB + ks * 16 + hk * 8];
#pragma unroll
        for (int nt = 0; nt < 2; ++nt)
#pragma unroll
            for (int ks = 0; ks < 2; ++ks)
                bfv[nt][ks] = *(const short8*)&Bs[(wn + nt * 32 + ln) * LDB + ks * 16 + hk * 8];
#pragma unroll
        for (int mt = 0; mt < 2; ++mt)
#pragma unroll
            for (int nt = 0; nt < 2; ++nt)
#pragma unroll
                for (int ks = 0; ks < 2; ++ks)
                    acc[mt][nt] = __builtin_amdgcn_mfma_f32_32x32x16_bf16(
                        af[mt][ks], bfv[nt][ks], acc[mt][nt], 0, 0, 0);
    }

#pragma unroll
    for (int mt = 0; mt < 2; ++mt)
#pragma unroll
        for (int nt = 0; nt < 2; ++nt)
#pragma unroll
            for (int e = 0; e < 16; ++e) {
                const int rl = mt * 32 + (e & 3) + ((e >> 2) << 3) + (hk << 2);
                Z[(((size_t)(s0 + rl)) << 8) + wn + nt * 32 + ln] = acc[mt][nt][e];
            }
}

// ---------------------------------------------------------------- GEMM1:
// h1 = p1 x W1head^T (K=128 streaming) + epilogue interp-gather from Z.
// launch_bounds(256,4): cap 128 regs/lane (64 arch + 64 acc) -> 4 waves/SIMD.
__global__ __launch_bounds__(256, 4) void k_gemm1(const float* __restrict__ p1,
                                                  const int* __restrict__ idx,
                                                  const float* __restrict__ wgt,
                                                  const unsigned short* __restrict__ w1b,
                                                  const float* __restrict__ b1p,
                                                  const float* __restrict__ Z,
                                                  unsigned short* __restrict__ h1b,
                                                  float* __restrict__ st1) {
    __shared__ __align__(16) unsigned short As[64 * LDB];    // 5 KB
    __shared__ __align__(16) unsigned short Bs[256 * LDB];   // 20 KB
    __shared__ float sSum[256], sSq[256];
    __shared__ __align__(16) unsigned sJW[64][8];            // {j0<<8, j1<<8, j2<<8, wa, wb, wc, -, -}

    const int tid = threadIdx.x;
    const int bid = blockIdx.x;                    // 2048 = 8 batches x 256
    const int b = bid & 7;                         // batch == XCD (d%8 round-robin)
    const int row0 = (b << 14) + ((bid >> 3) << 6);

    sSum[tid] = 0.f; sSq[tid] = 0.f;
    if (tid < 64) {
        const size_t o3 = (size_t)(row0 + tid) * 3;
        sJW[tid][0] = ((unsigned)idx[o3])     << 8;
        sJW[tid][1] = ((unsigned)idx[o3 + 1]) << 8;
        sJW[tid][2] = ((unsigned)idx[o3 + 2]) << 8;
        sJW[tid][3] = __float_as_uint(wgt[o3]);
        sJW[tid][4] = __float_as_uint(wgt[o3 + 1]);
        sJW[tid][5] = __float_as_uint(wgt[o3 + 2]);
    }

    const int wave = tid >> 6, lane = tid & 63;
    const int ln = lane & 31, hk = lane >> 5;
    const int wn = wave << 6;                 // wave-tile 64 rows x 64 cols
    const int r = tid >> 2, q = tid & 3;

    f32x16 acc[2][2];
#pragma unroll
    for (int mt = 0; mt < 2; ++mt)
#pragma unroll
        for (int nt = 0; nt < 2; ++nt)
#pragma unroll
            for (int e = 0; e < 16; ++e) acc[mt][nt][e] = 0.f;

    float4 ra[2];
    uint4 rb[4];
    auto prefetch = [&](int kc) {
        const unsigned short* bsrc = w1b + (size_t)tid * 384 + kc * 32;   // head cols 0..127
        rb[0] = *(const uint4*)(bsrc);
        rb[1] = *(const uint4*)(bsrc + 8);
        rb[2] = *(const uint4*)(bsrc + 16);
        rb[3] = *(const uint4*)(bsrc + 24);
        const float* asrc = p1 + (((size_t)(row0 + r)) << 7) + kc * 32 + q * 8;
        ra[0] = *(const float4*)(asrc);
        ra[1] = *(const float4*)(asrc + 4);
    };

    prefetch(0);

    for (int kc = 0; kc < 4; ++kc) {
        const uint4 pa = make_uint4(pk2(ra[0].x, ra[0].y), pk2(ra[0].z, ra[0].w),
                                    pk2(ra[1].x, ra[1].y), pk2(ra[1].z, ra[1].w));
        const uint4 b0 = rb[0], b1 = rb[1], b2 = rb[2], b3 = rb[3];

        __syncthreads();   // WAR: prior iteration's frag reads complete (also covers sJW write)
        *(uint4*)&As[r * LDB + q * 8] = pa;
        *(uint4*)&Bs[tid * LDB + 0]  = b0;
        *(uint4*)&Bs[tid * LDB + 8]  = b1;
        *(uint4*)&Bs[tid * LDB + 16] = b2;
        *(uint4*)&Bs[tid * LDB + 24] = b3;
        __syncthreads();

        if (kc < 3) prefetch(kc + 1);

        short8 af[2][2], bfv[2][2];
#pragma unroll
        for (int mt = 0; mt < 2; ++mt)
#pragma unroll
            for (int ks = 0; ks < 2; ++ks)
                af[mt][ks] = *(const short8*)&As[(mt * 32 + ln) * LDB + ks * 16 + hk * 8];
#pragma unroll
        for (int nt = 0; nt < 2; ++nt)
#pragma unroll
            for (int ks = 0; ks < 2; ++ks)
                bfv[nt][ks] = *(const short8*)&Bs[(wn + nt * 32 + ln) * LDB + ks * 16 + hk * 8];
#pragma unroll
        for (int mt = 0; mt < 2; ++mt)
#pragma unroll
            for (int nt = 0; nt < 2; ++nt)
#pragma unroll
                for (int ks = 0; ks < 2; ++ks)
                    acc[mt][nt] = __builtin_amdgcn_mfma_f32_32x32x16_bf16(
                        af[mt][ks], bfv[nt][ks], acc[mt][nt], 0, 0, 0);
    }

    // ---- epilogue v4: 8 batches of 4 consecutive rows; per batch:
    //      8 vector LDS reads -> 24 grouped global loads -> compute/store.
    const float* Zb = Z + ((size_t)b << 19);   // b * 2048 * 256
    const int c0 = wn + ln;
    const float bias0 = b1p[c0];
    const float bias1 = b1p[c0 + 32];
    float ps0 = 0.f, pq0 = 0.f, ps1 = 0.f, pq1 = 0.f;
#pragma unroll
    for (int mt = 0; mt < 2; ++mt) {
#pragma unroll
        for (int eg = 0; eg < 4; ++eg) {
            const int rbase = mt * 32 + eg * 8 + (hk << 2);   // 4 consecutive rows
            uint4 m0 = *(const uint4*)&sJW[rbase + 0][0];
            uint2 v0w = *(const uint2*)&sJW[rbase + 0][4];
            uint4 m1 = *(const uint4*)&sJW[rbase + 1][0];
            uint2 v1w = *(const uint2*)&sJW[rbase + 1][4];
            uint4 m2 = *(const uint4*)&sJW[rbase + 2][0];
            uint2 v2w = *(const uint2*)&sJW[rbase + 2][4];
            uint4 m3 = *(const uint4*)&sJW[rbase + 3][0];
            uint2 v3w = *(const uint2*)&sJW[rbase + 3][4];

            // grouped gather loads (static-indexed register array)
            float za[4][6];
            {
                const float* p00 = Zb + m0.x + c0;
                const float* p01 = Zb + m0.y + c0;
                const float* p02 = Zb + m0.z + c0;
                za[0][0] = p00[0]; za[0][1] = p00[32];
                za[0][2] = p01[0]; za[0][3] = p01[32];
                za[0][4] = p02[0]; za[0][5] = p02[32];
                const float* p10 = Zb + m1.x + c0;
                const float* p11 = Zb + m1.y + c0;
                const float* p12 = Zb + m1.z + c0;
                za[1][0] = p10[0]; za[1][1] = p10[32];
                za[1][2] = p11[0]; za[1][3] = p11[32];
                za[1][4] = p12[0]; za[1][5] = p12[32];
                const float* p20 = Zb + m2.x + c0;
                const float* p21 = Zb + m2.y + c0;
                const float* p22 = Zb + m2.z + c0;
                za[2][0] = p20[0]; za[2][1] = p20[32];
                za[2][2] = p21[0]; za[2][3] = p21[32];
                za[2][4] = p22[0]; za[2][5] = p22[32];
                const float* p30 = Zb + m3.x + c0;
                const float* p31 = Zb + m3.y + c0;
                const float* p32 = Zb + m3.z + c0;
                za[3][0] = p30[0]; za[3][1] = p30[32];
                za[3][2] = p31[0]; za[3][3] = p31[32];
                za[3][4] = p32[0]; za[3][5] = p32[32];
            }
            const float wA[4] = {__uint_as_float(m0.w), __uint_as_float(m1.w),
                                 __uint_as_float(m2.w), __uint_as_float(m3.w)};
            const float wB[4] = {__uint_as_float(v0w.x), __uint_as_float(v1w.x),
                                 __uint_as_float(v2w.x), __uint_as_float(v3w.x)};
            const float wC[4] = {__uint_as_float(v0w.y), __uint_as_float(v1w.y),
                                 __uint_as_float(v2w.y), __uint_as_float(v3w.y)};
#pragma unroll
            for (int j = 0; j < 4; ++j) {
                const int e = eg * 4 + j;
                const int rl = rbase + j;
                const float v0 = fmaf(wA[j], za[j][0], fmaf(wB[j], za[j][2], wC[j] * za[j][4]));
                const float v1 = fmaf(wA[j], za[j][1], fmaf(wB[j], za[j][3], wC[j] * za[j][5]));
                const float o0 = acc[mt][0][e] + bias0 + v0;
                const float o1 = acc[mt][1][e] + bias1 + v1;
                ps0 += o0; pq0 = fmaf(o0, o0, pq0);
                ps1 += o1; pq1 = fmaf(o1, o1, pq1);
                const size_t ro = ((size_t)(row0 + rl)) << 8;
                h1b[ro + c0]      = f2b(o0);
                h1b[ro + c0 + 32] = f2b(o1);
            }
        }
    }
    atomicAdd(&sSum[c0], ps0);      atomicAdd(&sSq[c0], pq0);
    atomicAdd(&sSum[c0 + 32], ps1); atomicAdd(&sSq[c0 + 32], pq1);
    __syncthreads();
    atomicAdd(&st1[tid], sSum[tid]);
    atomicAdd(&st1[256 + tid], sSq[tid]);
}

// ---------------------------------------------------------------- BN coef prep
__global__ void k_bnprep(const float* __restrict__ st, const float* __restrict__ g,
                         const float* __restrict__ be, float* __restrict__ bn,
                         int C, float invM) {
    int c = blockIdx.x * blockDim.x + threadIdx.x;
    if (c < C) {
        float mean = st[c] * invM;
        float var = st[C + c] * invM - mean * mean;
        float a = g[c] / sqrtf(var + 1e-5f);
        bn[c] = a;
        bn[C + c] = fmaf(-mean, a, be[c]);
    }
}

// ---------------------------------------------------------------- GEMM2: MFMA bf16, BN1+ReLU fused,
// register-prefetch pipeline, bf16 in/out, stats2. launch_bounds(256,4).
__global__ __launch_bounds__(256, 4) void k_gemm2(const unsigned short* __restrict__ h1b,
                                                  const unsigned short* __restrict__ w2b,
                                                  const float* __restrict__ b2p,
                                                  const float* __restrict__ bn1,
                                                  unsigned short* __restrict__ h2b,
                                                  float* __restrict__ st2) {
    __shared__ __align__(16) unsigned short As[128 * LDB];
    __shared__ __align__(16) unsigned short Bs[128 * LDB];
    __shared__ float sBNa[256], sBNb[256];
    __shared__ float sSum[128], sSq[128];

    const int tid = threadIdx.x;
    const int row0 = blockIdx.x * 128;

    sBNa[tid] = bn1[tid];
    sBNb[tid] = bn1[256 + tid];
    if (tid < 128) { sSum[tid] = 0.f; sSq[tid] = 0.f; }

    const int wave = tid >> 6, lane = tid & 63;
    const int ln = lane & 31, hk = lane >> 5;
    const int wm = (wave & 1) << 6, wn = (wave >> 1) << 6;
    const int r = tid >> 1, half = tid & 1;

    f32x16 acc[2][2];
#pragma unroll
    for (int mt = 0; mt < 2; ++mt)
#pragma unroll
        for (int nt = 0; nt < 2; ++nt)
#pragma unroll
            for (int e = 0; e < 16; ++e) acc[mt][nt][e] = 0.f;

    uint4 rA0, rA1, rB0, rB1;
    auto prefetch = [&](int kc) {
        const unsigned short* asrc = h1b + (size_t)(row0 + r) * 256 + kc * 32 + half * 16;
        rA0 = *(const uint4*)asrc;
        rA1 = *(const uint4*)(asrc + 8);
        const unsigned short* bsrc = w2b + (size_t)r * 256 + kc * 32 + half * 16;
        rB0 = *(const uint4*)bsrc;
        rB1 = *(const uint4*)(bsrc + 8);
    };

    prefetch(0);
    __syncthreads();   // sBN visible

    for (int kc = 0; kc < 8; ++kc) {
        const int k0 = kc * 32 + half * 16;
        unsigned pw[8] = {rA0.x, rA0.y, rA0.z, rA0.w, rA1.x, rA1.y, rA1.z, rA1.w};
        unsigned po[8];
#pragma unroll
        for (int gi = 0; gi < 8; ++gi) {
            float lo = b2f_lo(pw[gi]);
            float hi = b2f_hi(pw[gi]);
            lo = fmaxf(fmaf(sBNa[k0 + 2 * gi], lo, sBNb[k0 + 2 * gi]), 0.f);
            hi = fmaxf(fmaf(sBNa[k0 + 2 * gi + 1], hi, sBNb[k0 + 2 * gi + 1]), 0.f);
            po[gi] = pk2(lo, hi);
        }
        const uint4 pa0 = make_uint4(po[0], po[1], po[2], po[3]);
        const uint4 pa1 = make_uint4(po[4], po[5], po[6], po[7]);
        const uint4 qb0 = rB0, qb1 = rB1;

        __syncthreads();
        *(uint4*)&As[r * LDB + half * 16] = pa0;
        *(uint4*)&As[r * LDB + half * 16 + 8] = pa1;
        *(uint4*)&Bs[r * LDB + half * 16] = qb0;
        *(uint4*)&Bs[r * LDB + half * 16 + 8] = qb1;
        __syncthreads();

        if (kc < 7) prefetch(kc + 1);

        short8 af[2][2], bfv[2][2];
#pragma unroll
        for (int mt = 0; mt < 2; ++mt)
#pragma unroll
            for (int ks = 0; ks < 2; ++ks)
                af[mt][ks] = *(const short8*)&As[(wm + mt * 32 + ln) * LDB + ks * 16 + hk * 8];
#pragma unroll
        for (int nt = 0; nt < 2; ++nt)
#pragma unroll
            for (int ks = 0; ks < 2; ++ks)
                bfv[nt][ks] = *(const short8*)&Bs[(wn + nt * 32 + ln) * LDB + ks * 16 + hk * 8];
#pragma unroll
        for (int mt = 0; mt < 2; ++mt)
#pragma unroll
            for (int nt = 0; nt < 2; ++nt)
#pragma unroll
                for (int ks = 0; ks < 2; ++ks)
                    acc[mt][nt] = __builtin_amdgcn_mfma_f32_32x32x16_bf16(
                        af[mt][ks], bfv[nt][ks], acc[mt][nt], 0, 0, 0);
    }

#pragma unroll
    for (int nt = 0; nt < 2; ++nt) {
        const int col = wn + nt * 32 + ln;
        const float bias = b2p[col];
        float ps = 0.f, pq = 0.f;
#pragma unroll
        for (int mt = 0; mt < 2; ++mt) {
#pragma unroll
            for (int e = 0; e < 16; ++e) {
                const int rl = wm + mt * 32 + (e & 3) + ((e >> 2) << 3) + (hk << 2);
                const float o = acc[mt][nt][e] + bias;
                ps += o;
                pq = fmaf(o, o, pq);
                h2b[(((size_t)(row0 + rl)) << 7) + col] = f2b(o);
            }
        }
        atomicAdd(&sSum[col], ps);
        atomicAdd(&sSq[col], pq);
    }
    __syncthreads();
    if (tid < 128) {
        atomicAdd(&st2[tid], sSum[tid]);
        atomicAdd(&st2[128 + tid], sSq[tid]);
    }
}

// ---------------------------------------------------------------- pool pass (bf16 h2)
__global__ __launch_bounds__(256) void k_pool(const unsigned short* __restrict__ h2b,
                                              const float* __restrict__ bn2,
                                              float* __restrict__ psum,
                                              int* __restrict__ pmax) {
    const int b = blockIdx.y;
    const int n0 = blockIdx.x * 256;
    const int tid = threadIdx.x;
    const int c = tid & 127, rh = tid >> 7;
    const float a = bn2[c], bc = bn2[128 + c];
    const unsigned short* base = h2b + (((size_t)b * NN + n0 + rh) << 7) + c;
    float s = 0.f, m = 0.f;
    for (int i = 0; i < 128; ++i) {
        float v = __uint_as_float((unsigned)base[(size_t)i * 256] << 16);
        float x = fmaxf(fmaf(a, v, bc), 0.f);
        s += x;
        m = fmaxf(m, x);
    }
    __shared__ float rs[256];
    __shared__ float rm[256];
    rs[tid] = s; rm[tid] = m;
    __syncthreads();
    if (tid < 128) {
        float ts = rs[tid] + rs[tid + 128];
        float tm = fmaxf(rm[tid], rm[tid + 128]);
        atomicAdd(&psum[b * 128 + c], ts);
        atomicMax(&pmax[b * 128 + c], __float_as_int(tm));
    }
}

// ---------------------------------------------------------------- SE attention
__global__ __launch_bounds__(1024) void k_attn(const float* __restrict__ psum,
                                               const int* __restrict__ pmax,
                                               const float* __restrict__ fa1,
                                               const float* __restrict__ fa2,
                                               const float* __restrict__ bn2,
                                               float* __restrict__ sa,
                                               float* __restrict__ sb) {
    __shared__ float tS[128];
    const int tid = threadIdx.x;
    if (tid < 128) {
        const int b = tid >> 4, j = tid & 15;
        float da = 0.f, dm = 0.f;
        for (int cc = 0; cc < 128; ++cc) {
            float f = fa1[j * 128 + cc];
            da = fmaf(psum[b * 128 + cc] * (1.0f / 16384.0f), f, da);
            dm = fmaf(__int_as_float(pmax[b * 128 + cc]), f, dm);
        }
        tS[tid] = fmaxf(da, 0.f) + fmaxf(dm, 0.f);
    }
    __syncthreads();
    const int b = tid >> 7, c = tid & 127;
    float s = 0.f;
#pragma unroll
    for (int j = 0; j < 16; ++j) s = fmaf(tS[b * 16 + j], fa2[c * 16 + j], s);
    const float sc = 1.f / (1.f + expf(-s));
    sa[b * 128 + c] = bn2[c] * sc;
    sb[b * 128 + c] = bn2[128 + c] * sc;
}

// ---------------------------------------------------------------- final (bf16 h2 -> fp32 out)
__global__ void k_final(const unsigned short* __restrict__ h2b, const float* __restrict__ sa,
                        const float* __restrict__ sb, float* __restrict__ out) {
    const size_t i = (size_t)blockIdx.x * blockDim.x + threadIdx.x;  // 8-elem group
    const int cg = (int)(i & 15) * 8;
    const size_t row = i >> 4;
    const int b = (int)(row >> 14);
    const uint4 h = *(const uint4*)(h2b + (row << 7) + cg);
    const float4 A0 = *(const float4*)&sa[b * 128 + cg];
    const float4 A1 = *(const float4*)&sa[b * 128 + cg + 4];
    const float4 B0 = *(const float4*)&sb[b * 128 + cg];
    const float4 B1 = *(const float4*)&sb[b * 128 + cg + 4];
    float4 o0, o1;
    o0.x = fmaxf(fmaf(A0.x, b2f_lo(h.x), B0.x), 0.f);
    o0.y = fmaxf(fmaf(A0.y, b2f_hi(h.x), B0.y), 0.f);
    o0.z = fmaxf(fmaf(A0.z, b2f_lo(h.y), B0.z), 0.f);
    o0.w = fmaxf(fmaf(A0.w, b2f_hi(h.y), B0.w), 0.f);
    o1.x = fmaxf(fmaf(A1.x, b2f_lo(h.z), B1.x), 0.f);
    o1.y = fmaxf(fmaf(A1.y, b2f_hi(h.z), B1.y), 0.f);
    o1.z = fmaxf(fmaf(A1.z, b2f_lo(h.w), B1.z), 0.f);
    o1.w = fmaxf(fmaf(A1.w, b2f_hi(h.w), B1.w), 0.f);
    *(float4*)(out + (row << 7) + cg) = o0;
    *(float4*)(out + (row << 7) + cg + 4) = o1;
}

// ---------------------------------------------------------------- launch
extern "C" void kernel_launch(void* const* d_in, const int* in_sizes, int n_in,
                              void* d_out, int out_size, void* d_ws, size_t ws_size,
                              hipStream_t stream) {
    const float* xyz1 = (const float*)d_in[0];
    const float* xyz2 = (const float*)d_in[1];
    const float* p1   = (const float*)d_in[2];
    const float* p2   = (const float*)d_in[3];
    const float* w1   = (const float*)d_in[4];
    const float* b1   = (const float*)d_in[5];
    const float* g1   = (const float*)d_in[6];
    const float* be1  = (const float*)d_in[7];
    const float* w2   = (const float*)d_in[8];
    const float* b2   = (const float*)d_in[9];
    const float* g2   = (const float*)d_in[10];
    const float* be2  = (const float*)d_in[11];
    const float* fa1  = (const float*)d_in[12];
    const float* fa2  = (const float*)d_in[13];
    float* out = (float*)d_out;

    char* ws = (char*)d_ws;
    int*   idx  = (int*)ws;                                   // 1.57 MB
    float* wgt  = (float*)(ws + 1572864);                     // 1.57 MB
    unsigned short* h1b = (unsigned short*)(ws + 3145728);    // 67 MB bf16   [ends 70254592]
    unsigned short* h2b = (unsigned short*)(ws + 70254592);   // 33.5 MB bf16 [ends 103809024]
    // Z aliases h2b: Z (16.8 MB) is consumed by k_gemm1 (reads) strictly BEFORE
    // k_gemm2 writes h2b over it (stream-serial). No overlap in lifetime.
    float* Zbuf = (float*)(ws + 70254592);                    // 16.8 MB fp32
    float* st1  = (float*)(ws + 103809024);                   // 512 f
    float* bn1  = st1 + 512;                                  // 512 f
    float* st2  = bn1 + 512;                                  // 256 f
    float* bn2  = st2 + 256;                                  // 256 f
    float* psum = bn2 + 256;                                  // 1024 f
    int*   pmax = (int*)(psum + 1024);                        // 1024 i
    float* sa   = (float*)(pmax + 1024);                      // 1024 f
    float* sb   = sa + 1024;                                  // 1024 f
    unsigned short* w1b = (unsigned short*)(sb + 1024);       // 98304 bf16  [ends 104028160]
    unsigned short* w2b = w1b + 98304;                        // 32768 bf16  [ends 104093696]
    float4* xyz2p = (float4*)(ws + 104857600);                // 256 KB @ 100 MiB

    k_init<<<1, 1024, 0, stream>>>(st1, st2, psum, pmax);
    k_wprep<<<(H1 * 384 + 255) / 256, 256, 0, stream>>>(w1, w2, w1b, w2b);
    k_xyzprep<<<(BB * SS + 255) / 256, 256, 0, stream>>>(xyz2, xyz2p);
    k_knn<<<dim3(NN / 64, BB), 256, 0, stream>>>(xyz1, xyz2p, idx, wgt);
    k_zprep<<<BB * SS / 64, 256, 0, stream>>>(p2, w1b, Zbuf);
    k_gemm1<<<MM / 64, 256, 0, stream>>>(p1, idx, wgt, w1b, b1, Zbuf, h1b, st1);
    k_bnprep<<<1, 256, 0, stream>>>(st1, g1, be1, bn1, 256, 1.0f / (float)MM);
    k_gemm2<<<MM / 128, 256, 0, stream>>>(h1b, w2b, b2, bn1, h2b, st2);
    k_bnprep<<<1, 128, 0, stream>>>(st2, g2, be2, bn2, 128, 1.0f / (float)MM);
    k_pool<<<dim3(NN / 256, BB), 256, 0, stream>>>(h2b, bn2, psum, pmax);
    k_attn<<<1, 1024, 0, stream>>>(psum, pmax, fa1, fa2, bn2, sa, sb);
    k_final<<<(MM * H2 / 8) / 256, 256, 0, stream>>>(h2b, sa, sb, out);
}

// Round 9
// 388.621 us; speedup vs baseline: 1.0808x; 1.0808x over previous
//
#include <hip/hip_runtime.h>
#include <math.h>

// Problem constants (fixed by setup_inputs)
constexpr int BB = 8;
constexpr int NN = 16384;
constexpr int SS = 2048;
constexpr int D2 = 256;
constexpr int H1 = 256;
constexpr int H2 = 128;
constexpr int MM = BB * NN;   // 131072 rows
constexpr int LDB = 40;       // LDS leading dim (bf16 elems): 80 B, 16B-aligned

typedef __attribute__((ext_vector_type(8))) short short8;    // bf16x8 frag (4 VGPRs)
typedef __attribute__((ext_vector_type(16))) float f32x16;   // 32x32 accumulator

__device__ __forceinline__ unsigned short f2b(float f) {     // fp32 -> bf16 RNE
    union { float f; unsigned u; } v; v.f = f;
    unsigned r = v.u + 0x7FFFu + ((v.u >> 16) & 1u);
    return (unsigned short)(r >> 16);
}
__device__ __forceinline__ unsigned pk2(float lo, float hi) {
    return (unsigned)f2b(lo) | ((unsigned)f2b(hi) << 16);
}
__device__ __forceinline__ float b2f_lo(unsigned p) { return __uint_as_float(p << 16); }
__device__ __forceinline__ float b2f_hi(unsigned p) { return __uint_as_float(p & 0xFFFF0000u); }

__device__ __forceinline__ unsigned umed3(unsigned a, unsigned b, unsigned c) {
    unsigned d; asm("v_med3_u32 %0, %1, %2, %3" : "=v"(d) : "v"(a), "v"(b), "v"(c)); return d;
}

// ---------------------------------------------------------------- init
__global__ void k_init(float* __restrict__ st1, float* __restrict__ st2,
                       float* __restrict__ psum, int* __restrict__ pmax) {
    int t = threadIdx.x;
    if (t < 512) st1[t] = 0.f;
    if (t < 256) st2[t] = 0.f;
    if (t < 1024) { psum[t] = 0.f; pmax[t] = 0; }
}

// ---------------------------------------------------------------- weight fp32->bf16 prep
__global__ void k_wprep(const float* __restrict__ w1, const float* __restrict__ w2,
                        unsigned short* __restrict__ w1b, unsigned short* __restrict__ w2b) {
    int i = blockIdx.x * 256 + threadIdx.x;
    if (i < H1 * 384) w1b[i] = f2b(w1[i]);
    if (i < H2 * 256) w2b[i] = f2b(w2[i]);
}

// ---------------------------------------------------------------- xyz2 -> float4 pack (for scalar loads)
__global__ void k_xyzprep(const float* __restrict__ xyz2, float4* __restrict__ xyz2p) {
    int i = blockIdx.x * 256 + threadIdx.x;   // 0 .. BB*SS-1
    if (i < BB * SS) {
        xyz2p[i] = make_float4(xyz2[i * 3], xyz2[i * 3 + 1], xyz2[i * 3 + 2], 0.f);
    }
}

// ---------------------------------------------------------------- 3-NN
// Wave-uniform float4 candidate stream; top-4 insert via {min, med3, med3, med3}.
__global__ __launch_bounds__(256) void k_knn(const float* __restrict__ xyz1,
                                             const float4* __restrict__ xyz2p,
                                             int* __restrict__ idx,
                                             float* __restrict__ wgt) {
    __shared__ unsigned cand[64][16];             // 4 KB: [query][chunk*4+t]
    const int b = blockIdx.y;
    const int tid = threadIdx.x;
    const int ql = tid & 63;                      // query-local
    const int n = blockIdx.x * 64 + ql;

    const float* q = xyz1 + ((size_t)b * NN + n) * 3;
    const float qx = q[0], qy = q[1], qz = q[2];

    // wave-uniform chunk base -> scalar loads through K$
    const int chunk = __builtin_amdgcn_readfirstlane(tid >> 6);   // 0..3
    const float4* cp = xyz2p + ((size_t)b << 11) + (chunk << 9);

    unsigned k0 = 0xFFFFFFFFu, k1 = 0xFFFFFFFFu, k2 = 0xFFFFFFFFu, k3 = 0xFFFFFFFFu;
#pragma unroll 4
    for (int j = 0; j < 512; ++j) {
        const float4 p = cp[j];
        const float dx = qx - p.x;
        const float dy = qy - p.y;
        const float dz = qz - p.z;
        const float d = fmaf(dx, dx, fmaf(dy, dy, dz * dz));
        const unsigned key = (__float_as_uint(d) & 0xFFFFFE00u) | (unsigned)j;
        // sorted top-4 insert: {min, med3, med3, med3} (4 independent ops)
        const unsigned n0 = min(k0, key);
        const unsigned n1 = umed3(k0, k1, key);
        const unsigned n2 = umed3(k1, k2, key);
        const unsigned n3 = umed3(k2, k3, key);
        k0 = n0; k1 = n1; k2 = n2; k3 = n3;
    }
    unsigned* cq = cand[ql] + chunk * 4;
    cq[0] = k0; cq[1] = k1; cq[2] = k2; cq[3] = k3;
    __syncthreads();

    if (tid < 64) {
        const double qxd = (double)qx, qyd = (double)qy, qzd = (double)qz;
        double t0 = 1e300, t1 = 1e300, t2 = 1e300;
        int i0 = 0, i1 = 0, i2 = 0;
#pragma unroll
        for (int c = 0; c < 16; ++c) {
            const int s = ((c >> 2) << 9) + (int)(cand[tid][c] & 0x1FFu);
            const float4 p = xyz2p[((size_t)b << 11) + s];
            const double dx = qxd - (double)p.x;
            const double dy = qyd - (double)p.y;
            const double dz = qzd - (double)p.z;
            const double d = fma(dx, dx, fma(dy, dy, dz * dz));
            if (d < t2) {
                if (d < t0)      { t2 = t1; i2 = i1; t1 = t0; i1 = i0; t0 = d; i0 = s; }
                else if (d < t1) { t2 = t1; i2 = i1; t1 = d; i1 = s; }
                else             { t2 = d; i2 = s; }
            }
        }
        const double r0 = 1.0 / (t0 + 1e-8);
        const double r1 = 1.0 / (t1 + 1e-8);
        const double r2 = 1.0 / (t2 + 1e-8);
        const double inv = 1.0 / (r0 + r1 + r2);
        const size_t o = ((size_t)b * NN + n) * 3;
        idx[o + 0] = i0; idx[o + 1] = i1; idx[o + 2] = i2;
        wgt[o + 0] = (float)(r0 * inv);
        wgt[o + 1] = (float)(r1 * inv);
        wgt[o + 2] = (float)(r2 * inv);
    }
}

// ---------------------------------------------------------------- Z-prep: Z = p2 x W1tail^T
// XCD-aligned: block d -> XCD d%8 (HW round-robin), batch = d&7, so batch b's
// Z slice is produced (and likely cached) on XCD b.
__global__ __launch_bounds__(256) void k_zprep(const float* __restrict__ p2,
                                               const unsigned short* __restrict__ w1b,
                                               float* __restrict__ Z) {
    __shared__ __align__(16) unsigned short As[64 * LDB];    // 5 KB
    __shared__ __align__(16) unsigned short Bs[256 * LDB];   // 20 KB
    const int tid = threadIdx.x;
    const int bid = blockIdx.x;                   // 256 = 8 batches x 32
    const int s0 = ((bid & 7) << 11) + ((bid >> 3) << 6);
    const int wave = tid >> 6, lane = tid & 63;
    const int ln = lane & 31, hk = lane >> 5;
    const int wn = wave << 6;                 // wave-tile 64 rows x 64 cols
    const int r = tid >> 2, q = tid & 3;

    f32x16 acc[2][2];
#pragma unroll
    for (int mt = 0; mt < 2; ++mt)
#pragma unroll
        for (int nt = 0; nt < 2; ++nt)
#pragma unroll
            for (int e = 0; e < 16; ++e) acc[mt][nt][e] = 0.f;

    float4 ra[2];
    uint4 rb[4];
    auto prefetch = [&](int kc) {
        const unsigned short* bsrc = w1b + (size_t)tid * 384 + 128 + kc * 32;
        rb[0] = *(const uint4*)(bsrc);
        rb[1] = *(const uint4*)(bsrc + 8);
        rb[2] = *(const uint4*)(bsrc + 16);
        rb[3] = *(const uint4*)(bsrc + 24);
        const float* asrc = p2 + (((size_t)(s0 + r)) << 8) + kc * 32 + q * 8;
        ra[0] = *(const float4*)(asrc);
        ra[1] = *(const float4*)(asrc + 4);
    };

    prefetch(0);

    for (int kc = 0; kc < 8; ++kc) {
        const uint4 pa = make_uint4(pk2(ra[0].x, ra[0].y), pk2(ra[0].z, ra[0].w),
                                    pk2(ra[1].x, ra[1].y), pk2(ra[1].z, ra[1].w));
        const uint4 b0 = rb[0], b1 = rb[1], b2 = rb[2], b3 = rb[3];

        __syncthreads();
        *(uint4*)&As[r * LDB + q * 8] = pa;
        *(uint4*)&Bs[tid * LDB + 0]  = b0;
        *(uint4*)&Bs[tid * LDB + 8]  = b1;
        *(uint4*)&Bs[tid * LDB + 16] = b2;
        *(uint4*)&Bs[tid * LDB + 24] = b3;
        __syncthreads();

        if (kc < 7) prefetch(kc + 1);

        short8 af[2][2], bfv[2][2];
#pragma unroll
        for (int mt = 0; mt < 2; ++mt)
#pragma unroll
            for (int ks = 0; ks < 2; ++ks)
                af[mt][ks] = *(const short8*)&As[(mt * 32 + ln) * LDB + ks * 16 + hk * 8];
#pragma unroll
        for (int nt = 0; nt < 2; ++nt)
#pragma unroll
            for (int ks = 0; ks < 2; ++ks)
                bfv[nt][ks] = *(const short8*)&Bs[(wn + nt * 32 + ln) * LDB + ks * 16 + hk * 8];
#pragma unroll
        for (int mt = 0; mt < 2; ++mt)
#pragma unroll
            for (int nt = 0; nt < 2; ++nt)
#pragma unroll
                for (int ks = 0; ks < 2; ++ks)
                    acc[mt][nt] = __builtin_amdgcn_mfma_f32_32x32x16_bf16(
                        af[mt][ks], bfv[nt][ks], acc[mt][nt], 0, 0, 0);
    }

#pragma unroll
    for (int mt = 0; mt < 2; ++mt)
#pragma unroll
        for (int nt = 0; nt < 2; ++nt)
#pragma unroll
            for (int e = 0; e < 16; ++e) {
                const int rl = mt * 32 + (e & 3) + ((e >> 2) << 3) + (hk << 2);
                Z[(((size_t)(s0 + rl)) << 8) + wn + nt * 32 + ln] = acc[mt][nt][e];
            }
}

// ---------------------------------------------------------------- GEMM1:
// h1 = p1 x W1head^T (K=128 streaming) + epilogue interp-gather from Z.
// Epilogue v5: 2-row batches (live set ~12 floats) so 64 arch VGPRs fit
// WITHOUT spill under launch_bounds(256,4) -> 4 waves/SIMD.
__global__ __launch_bounds__(256, 4) void k_gemm1(const float* __restrict__ p1,
                                                  const int* __restrict__ idx,
                                                  const float* __restrict__ wgt,
                                                  const unsigned short* __restrict__ w1b,
                                                  const float* __restrict__ b1p,
                                                  const float* __restrict__ Z,
                                                  unsigned short* __restrict__ h1b,
                                                  float* __restrict__ st1) {
    __shared__ __align__(16) unsigned short As[64 * LDB];    // 5 KB
    __shared__ __align__(16) unsigned short Bs[256 * LDB];   // 20 KB
    __shared__ float sSum[256], sSq[256];
    __shared__ __align__(16) unsigned sJW[64][8];            // {j0<<8, j1<<8, j2<<8, wa, wb, wc, -, -}

    const int tid = threadIdx.x;
    const int bid = blockIdx.x;                    // 2048 = 8 batches x 256
    const int b = bid & 7;                         // batch == XCD (d%8 round-robin)
    const int row0 = (b << 14) + ((bid >> 3) << 6);

    sSum[tid] = 0.f; sSq[tid] = 0.f;
    if (tid < 64) {
        const size_t o3 = (size_t)(row0 + tid) * 3;
        sJW[tid][0] = ((unsigned)idx[o3])     << 8;
        sJW[tid][1] = ((unsigned)idx[o3 + 1]) << 8;
        sJW[tid][2] = ((unsigned)idx[o3 + 2]) << 8;
        sJW[tid][3] = __float_as_uint(wgt[o3]);
        sJW[tid][4] = __float_as_uint(wgt[o3 + 1]);
        sJW[tid][5] = __float_as_uint(wgt[o3 + 2]);
    }

    const int wave = tid >> 6, lane = tid & 63;
    const int ln = lane & 31, hk = lane >> 5;
    const int wn = wave << 6;                 // wave-tile 64 rows x 64 cols
    const int r = tid >> 2, q = tid & 3;

    f32x16 acc[2][2];
#pragma unroll
    for (int mt = 0; mt < 2; ++mt)
#pragma unroll
        for (int nt = 0; nt < 2; ++nt)
#pragma unroll
            for (int e = 0; e < 16; ++e) acc[mt][nt][e] = 0.f;

    float4 ra[2];
    uint4 rb[4];
    auto prefetch = [&](int kc) {
        const unsigned short* bsrc = w1b + (size_t)tid * 384 + kc * 32;   // head cols 0..127
        rb[0] = *(const uint4*)(bsrc);
        rb[1] = *(const uint4*)(bsrc + 8);
        rb[2] = *(const uint4*)(bsrc + 16);
        rb[3] = *(const uint4*)(bsrc + 24);
        const float* asrc = p1 + (((size_t)(row0 + r)) << 7) + kc * 32 + q * 8;
        ra[0] = *(const float4*)(asrc);
        ra[1] = *(const float4*)(asrc + 4);
    };

    prefetch(0);

    for (int kc = 0; kc < 4; ++kc) {
        const uint4 pa = make_uint4(pk2(ra[0].x, ra[0].y), pk2(ra[0].z, ra[0].w),
                                    pk2(ra[1].x, ra[1].y), pk2(ra[1].z, ra[1].w));
        const uint4 b0 = rb[0], b1 = rb[1], b2 = rb[2], b3 = rb[3];

        __syncthreads();   // WAR: prior iteration's frag reads complete (also covers sJW write)
        *(uint4*)&As[r * LDB + q * 8] = pa;
        *(uint4*)&Bs[tid * LDB + 0]  = b0;
        *(uint4*)&Bs[tid * LDB + 8]  = b1;
        *(uint4*)&Bs[tid * LDB + 16] = b2;
        *(uint4*)&Bs[tid * LDB + 24] = b3;
        __syncthreads();

        if (kc < 3) prefetch(kc + 1);

        short8 af[2][2], bfv[2][2];
#pragma unroll
        for (int mt = 0; mt < 2; ++mt)
#pragma unroll
            for (int ks = 0; ks < 2; ++ks)
                af[mt][ks] = *(const short8*)&As[(mt * 32 + ln) * LDB + ks * 16 + hk * 8];
#pragma unroll
        for (int nt = 0; nt < 2; ++nt)
#pragma unroll
            for (int ks = 0; ks < 2; ++ks)
                bfv[nt][ks] = *(const short8*)&Bs[(wn + nt * 32 + ln) * LDB + ks * 16 + hk * 8];
#pragma unroll
        for (int mt = 0; mt < 2; ++mt)
#pragma unroll
            for (int nt = 0; nt < 2; ++nt)
#pragma unroll
                for (int ks = 0; ks < 2; ++ks)
                    acc[mt][nt] = __builtin_amdgcn_mfma_f32_32x32x16_bf16(
                        af[mt][ks], bfv[nt][ks], acc[mt][nt], 0, 0, 0);
    }

    // ---- epilogue v5: 16 batches of 2 consecutive rows; per batch:
    //      4 vector LDS reads -> 12 grouped global loads -> compute/store.
    //      Element order identical to v4 -> bitwise-same stats/output.
    const float* Zb = Z + ((size_t)b << 19);   // b * 2048 * 256
    const int c0 = wn + ln;
    const float bias0 = b1p[c0];
    const float bias1 = b1p[c0 + 32];
    float ps0 = 0.f, pq0 = 0.f, ps1 = 0.f, pq1 = 0.f;
#pragma unroll
    for (int mt = 0; mt < 2; ++mt) {
#pragma unroll
        for (int eg = 0; eg < 4; ++eg) {
#pragma unroll
            for (int hh = 0; hh < 2; ++hh) {
                const int rbase = mt * 32 + eg * 8 + (hk << 2) + hh * 2;  // 2 rows
                uint4 m0 = *(const uint4*)&sJW[rbase + 0][0];
                uint2 v0w = *(const uint2*)&sJW[rbase + 0][4];
                uint4 m1 = *(const uint4*)&sJW[rbase + 1][0];
                uint2 v1w = *(const uint2*)&sJW[rbase + 1][4];

                float za[2][6];
                {
                    const float* p00 = Zb + m0.x + c0;
                    const float* p01 = Zb + m0.y + c0;
                    const float* p02 = Zb + m0.z + c0;
                    za[0][0] = p00[0]; za[0][1] = p00[32];
                    za[0][2] = p01[0]; za[0][3] = p01[32];
                    za[0][4] = p02[0]; za[0][5] = p02[32];
                    const float* p10 = Zb + m1.x + c0;
                    const float* p11 = Zb + m1.y + c0;
                    const float* p12 = Zb + m1.z + c0;
                    za[1][0] = p10[0]; za[1][1] = p10[32];
                    za[1][2] = p11[0]; za[1][3] = p11[32];
                    za[1][4] = p12[0]; za[1][5] = p12[32];
                }
                const float wA[2] = {__uint_as_float(m0.w), __uint_as_float(m1.w)};
                const float wB[2] = {__uint_as_float(v0w.x), __uint_as_float(v1w.x)};
                const float wC[2] = {__uint_as_float(v0w.y), __uint_as_float(v1w.y)};
#pragma unroll
                for (int j = 0; j < 2; ++j) {
                    const int e = eg * 4 + hh * 2 + j;
                    const int rl = rbase + j;
                    const float v0 = fmaf(wA[j], za[j][0], fmaf(wB[j], za[j][2], wC[j] * za[j][4]));
                    const float v1 = fmaf(wA[j], za[j][1], fmaf(wB[j], za[j][3], wC[j] * za[j][5]));
                    const float o0 = acc[mt][0][e] + bias0 + v0;
                    const float o1 = acc[mt][1][e] + bias1 + v1;
                    ps0 += o0; pq0 = fmaf(o0, o0, pq0);
                    ps1 += o1; pq1 = fmaf(o1, o1, pq1);
                    const size_t ro = ((size_t)(row0 + rl)) << 8;
                    h1b[ro + c0]      = f2b(o0);
                    h1b[ro + c0 + 32] = f2b(o1);
                }
            }
        }
    }
    atomicAdd(&sSum[c0], ps0);      atomicAdd(&sSq[c0], pq0);
    atomicAdd(&sSum[c0 + 32], ps1); atomicAdd(&sSq[c0 + 32], pq1);
    __syncthreads();
    atomicAdd(&st1[tid], sSum[tid]);
    atomicAdd(&st1[256 + tid], sSq[tid]);
}

// ---------------------------------------------------------------- BN coef prep
__global__ void k_bnprep(const float* __restrict__ st, const float* __restrict__ g,
                         const float* __restrict__ be, float* __restrict__ bn,
                         int C, float invM) {
    int c = blockIdx.x * blockDim.x + threadIdx.x;
    if (c < C) {
        float mean = st[c] * invM;
        float var = st[C + c] * invM - mean * mean;
        float a = g[c] / sqrtf(var + 1e-5f);
        bn[c] = a;
        bn[C + c] = fmaf(-mean, a, be[c]);
    }
}

// ---------------------------------------------------------------- GEMM2: MFMA bf16, BN1+ReLU fused,
// register-prefetch pipeline, bf16 in/out, stats2
__global__ __launch_bounds__(256) void k_gemm2(const unsigned short* __restrict__ h1b,
                                               const unsigned short* __restrict__ w2b,
                                               const float* __restrict__ b2p,
                                               const float* __restrict__ bn1,
                                               unsigned short* __restrict__ h2b,
                                               float* __restrict__ st2) {
    __shared__ __align__(16) unsigned short As[128 * LDB];
    __shared__ __align__(16) unsigned short Bs[128 * LDB];
    __shared__ float sBNa[256], sBNb[256];
    __shared__ float sSum[128], sSq[128];

    const int tid = threadIdx.x;
    const int row0 = blockIdx.x * 128;

    sBNa[tid] = bn1[tid];
    sBNb[tid] = bn1[256 + tid];
    if (tid < 128) { sSum[tid] = 0.f; sSq[tid] = 0.f; }

    const int wave = tid >> 6, lane = tid & 63;
    const int ln = lane & 31, hk = lane >> 5;
    const int wm = (wave & 1) << 6, wn = (wave >> 1) << 6;
    const int r = tid >> 1, half = tid & 1;

    f32x16 acc[2][2];
#pragma unroll
    for (int mt = 0; mt < 2; ++mt)
#pragma unroll
        for (int nt = 0; nt < 2; ++nt)
#pragma unroll
            for (int e = 0; e < 16; ++e) acc[mt][nt][e] = 0.f;

    uint4 rA0, rA1, rB0, rB1;
    auto prefetch = [&](int kc) {
        const unsigned short* asrc = h1b + (size_t)(row0 + r) * 256 + kc * 32 + half * 16;
        rA0 = *(const uint4*)asrc;
        rA1 = *(const uint4*)(asrc + 8);
        const unsigned short* bsrc = w2b + (size_t)r * 256 + kc * 32 + half * 16;
        rB0 = *(const uint4*)bsrc;
        rB1 = *(const uint4*)(bsrc + 8);
    };

    prefetch(0);
    __syncthreads();   // sBN visible

    for (int kc = 0; kc < 8; ++kc) {
        const int k0 = kc * 32 + half * 16;
        unsigned pw[8] = {rA0.x, rA0.y, rA0.z, rA0.w, rA1.x, rA1.y, rA1.z, rA1.w};
        unsigned po[8];
#pragma unroll
        for (int gi = 0; gi < 8; ++gi) {
            float lo = b2f_lo(pw[gi]);
            float hi = b2f_hi(pw[gi]);
            lo = fmaxf(fmaf(sBNa[k0 + 2 * gi], lo, sBNb[k0 + 2 * gi]), 0.f);
            hi = fmaxf(fmaf(sBNa[k0 + 2 * gi + 1], hi, sBNb[k0 + 2 * gi + 1]), 0.f);
            po[gi] = pk2(lo, hi);
        }
        const uint4 pa0 = make_uint4(po[0], po[1], po[2], po[3]);
        const uint4 pa1 = make_uint4(po[4], po[5], po[6], po[7]);
        const uint4 qb0 = rB0, qb1 = rB1;

        __syncthreads();
        *(uint4*)&As[r * LDB + half * 16] = pa0;
        *(uint4*)&As[r * LDB + half * 16 + 8] = pa1;
        *(uint4*)&Bs[r * LDB + half * 16] = qb0;
        *(uint4*)&Bs[r * LDB + half * 16 + 8] = qb1;
        __syncthreads();

        if (kc < 7) prefetch(kc + 1);

        short8 af[2][2], bfv[2][2];
#pragma unroll
        for (int mt = 0; mt < 2; ++mt)
#pragma unroll
            for (int ks = 0; ks < 2; ++ks)
                af[mt][ks] = *(const short8*)&As[(wm + mt * 32 + ln) * LDB + ks * 16 + hk * 8];
#pragma unroll
        for (int nt = 0; nt < 2; ++nt)
#pragma unroll
            for (int ks = 0; ks < 2; ++ks)
                bfv[nt][ks] = *(const short8*)&Bs[(wn + nt * 32 + ln) * LDB + ks * 16 + hk * 8];
#pragma unroll
        for (int mt = 0; mt < 2; ++mt)
#pragma unroll
            for (int nt = 0; nt < 2; ++nt)
#pragma unroll
                for (int ks = 0; ks < 2; ++ks)
                    acc[mt][nt] = __builtin_amdgcn_mfma_f32_32x32x16_bf16(
                        af[mt][ks], bfv[nt][ks], acc[mt][nt], 0, 0, 0);
    }

#pragma unroll
    for (int nt = 0; nt < 2; ++nt) {
        const int col = wn + nt * 32 + ln;
        const float bias = b2p[col];
        float ps = 0.f, pq = 0.f;
#pragma unroll
        for (int mt = 0; mt < 2; ++mt) {
#pragma unroll
            for (int e = 0; e < 16; ++e) {
                const int rl = wm + mt * 32 + (e & 3) + ((e >> 2) << 3) + (hk << 2);
                const float o = acc[mt][nt][e] + bias;
                ps += o;
                pq = fmaf(o, o, pq);
                h2b[(((size_t)(row0 + rl)) << 7) + col] = f2b(o);
            }
        }
        atomicAdd(&sSum[col], ps);
        atomicAdd(&sSq[col], pq);
    }
    __syncthreads();
    if (tid < 128) {
        atomicAdd(&st2[tid], sSum[tid]);
        atomicAdd(&st2[128 + tid], sSq[tid]);
    }
}

// ---------------------------------------------------------------- pool pass (bf16 h2)
__global__ __launch_bounds__(256) void k_pool(const unsigned short* __restrict__ h2b,
                                              const float* __restrict__ bn2,
                                              float* __restrict__ psum,
                                              int* __restrict__ pmax) {
    const int b = blockIdx.y;
    const int n0 = blockIdx.x * 256;
    const int tid = threadIdx.x;
    const int c = tid & 127, rh = tid >> 7;
    const float a = bn2[c], bc = bn2[128 + c];
    const unsigned short* base = h2b + (((size_t)b * NN + n0 + rh) << 7) + c;
    float s = 0.f, m = 0.f;
    for (int i = 0; i < 128; ++i) {
        float v = __uint_as_float((unsigned)base[(size_t)i * 256] << 16);
        float x = fmaxf(fmaf(a, v, bc), 0.f);
        s += x;
        m = fmaxf(m, x);
    }
    __shared__ float rs[256];
    __shared__ float rm[256];
    rs[tid] = s; rm[tid] = m;
    __syncthreads();
    if (tid < 128) {
        float ts = rs[tid] + rs[tid + 128];
        float tm = fmaxf(rm[tid], rm[tid + 128]);
        atomicAdd(&psum[b * 128 + c], ts);
        atomicMax(&pmax[b * 128 + c], __float_as_int(tm));
    }
}

// ---------------------------------------------------------------- SE attention
__global__ __launch_bounds__(1024) void k_attn(const float* __restrict__ psum,
                                               const int* __restrict__ pmax,
                                               const float* __restrict__ fa1,
                                               const float* __restrict__ fa2,
                                               const float* __restrict__ bn2,
                                               float* __restrict__ sa,
                                               float* __restrict__ sb) {
    __shared__ float tS[128];
    const int tid = threadIdx.x;
    if (tid < 128) {
        const int b = tid >> 4, j = tid & 15;
        float da = 0.f, dm = 0.f;
        for (int cc = 0; cc < 128; ++cc) {
            float f = fa1[j * 128 + cc];
            da = fmaf(psum[b * 128 + cc] * (1.0f / 16384.0f), f, da);
            dm = fmaf(__int_as_float(pmax[b * 128 + cc]), f, dm);
        }
        tS[tid] = fmaxf(da, 0.f) + fmaxf(dm, 0.f);
    }
    __syncthreads();
    const int b = tid >> 7, c = tid & 127;
    float s = 0.f;
#pragma unroll
    for (int j = 0; j < 16; ++j) s = fmaf(tS[b * 16 + j], fa2[c * 16 + j], s);
    const float sc = 1.f / (1.f + expf(-s));
    sa[b * 128 + c] = bn2[c] * sc;
    sb[b * 128 + c] = bn2[128 + c] * sc;
}

// ---------------------------------------------------------------- final (bf16 h2 -> fp32 out)
__global__ void k_final(const unsigned short* __restrict__ h2b, const float* __restrict__ sa,
                        const float* __restrict__ sb, float* __restrict__ out) {
    const size_t i = (size_t)blockIdx.x * blockDim.x + threadIdx.x;  // 8-elem group
    const int cg = (int)(i & 15) * 8;
    const size_t row = i >> 4;
    const int b = (int)(row >> 14);
    const uint4 h = *(const uint4*)(h2b + (row << 7) + cg);
    const float4 A0 = *(const float4*)&sa[b * 128 + cg];
    const float4 A1 = *(const float4*)&sa[b * 128 + cg + 4];
    const float4 B0 = *(const float4*)&sb[b * 128 + cg];
    const float4 B1 = *(const float4*)&sb[b * 128 + cg + 4];
    float4 o0, o1;
    o0.x = fmaxf(fmaf(A0.x, b2f_lo(h.x), B0.x), 0.f);
    o0.y = fmaxf(fmaf(A0.y, b2f_hi(h.x), B0.y), 0.f);
    o0.z = fmaxf(fmaf(A0.z, b2f_lo(h.y), B0.z), 0.f);
    o0.w = fmaxf(fmaf(A0.w, b2f_hi(h.y), B0.w), 0.f);
    o1.x = fmaxf(fmaf(A1.x, b2f_lo(h.z), B1.x), 0.f);
    o1.y = fmaxf(fmaf(A1.y, b2f_hi(h.z), B1.y), 0.f);
    o1.z = fmaxf(fmaf(A1.z, b2f_lo(h.w), B1.z), 0.f);
    o1.w = fmaxf(fmaf(A1.w, b2f_hi(h.w), B1.w), 0.f);
    *(float4*)(out + (row << 7) + cg) = o0;
    *(float4*)(out + (row << 7) + cg + 4) = o1;
}

// ---------------------------------------------------------------- launch
extern "C" void kernel_launch(void* const* d_in, const int* in_sizes, int n_in,
                              void* d_out, int out_size, void* d_ws, size_t ws_size,
                              hipStream_t stream) {
    const float* xyz1 = (const float*)d_in[0];
    const float* xyz2 = (const float*)d_in[1];
    const float* p1   = (const float*)d_in[2];
    const float* p2   = (const float*)d_in[3];
    const float* w1   = (const float*)d_in[4];
    const float* b1   = (const float*)d_in[5];
    const float* g1   = (const float*)d_in[6];
    const float* be1  = (const float*)d_in[7];
    const float* w2   = (const float*)d_in[8];
    const float* b2   = (const float*)d_in[9];
    const float* g2   = (const float*)d_in[10];
    const float* be2  = (const float*)d_in[11];
    const float* fa1  = (const float*)d_in[12];
    const float* fa2  = (const float*)d_in[13];
    float* out = (float*)d_out;

    char* ws = (char*)d_ws;
    int*   idx  = (int*)ws;                                   // 1.57 MB
    float* wgt  = (float*)(ws + 1572864);                     // 1.57 MB
    unsigned short* h1b = (unsigned short*)(ws + 3145728);    // 67 MB bf16   [ends 70254592]
    unsigned short* h2b = (unsigned short*)(ws + 70254592);   // 33.5 MB bf16 [ends 103809024]
    // Z aliases h2b: Z (16.8 MB) is consumed by k_gemm1 (reads) strictly BEFORE
    // k_gemm2 writes h2b over it (stream-serial). No overlap in lifetime.
    float* Zbuf = (float*)(ws + 70254592);                    // 16.8 MB fp32
    float* st1  = (float*)(ws + 103809024);                   // 512 f
    float* bn1  = st1 + 512;                                  // 512 f
    float* st2  = bn1 + 512;                                  // 256 f
    float* bn2  = st2 + 256;                                  // 256 f
    float* psum = bn2 + 256;                                  // 1024 f
    int*   pmax = (int*)(psum + 1024);                        // 1024 i
    float* sa   = (float*)(pmax + 1024);                      // 1024 f
    float* sb   = sa + 1024;                                  // 1024 f
    unsigned short* w1b = (unsigned short*)(sb + 1024);       // 98304 bf16  [ends 104028160]
    unsigned short* w2b = w1b + 98304;                        // 32768 bf16  [ends 104093696]
    float4* xyz2p = (float4*)(ws + 104857600);                // 256 KB @ 100 MiB

    k_init<<<1, 1024, 0, stream>>>(st1, st2, psum, pmax);
    k_wprep<<<(H1 * 384 + 255) / 256, 256, 0, stream>>>(w1, w2, w1b, w2b);
    k_xyzprep<<<(BB * SS + 255) / 256, 256, 0, stream>>>(xyz2, xyz2p);
    k_knn<<<dim3(NN / 64, BB), 256, 0, stream>>>(xyz1, xyz2p, idx, wgt);
    k_zprep<<<BB * SS / 64, 256, 0, stream>>>(p2, w1b, Zbuf);
    k_gemm1<<<MM / 64, 256, 0, stream>>>(p1, idx, wgt, w1b, b1, Zbuf, h1b, st1);
    k_bnprep<<<1, 256, 0, stream>>>(st1, g1, be1, bn1, 256, 1.0f / (float)MM);
    k_gemm2<<<MM / 128, 256, 0, stream>>>(h1b, w2b, b2, bn1, h2b, st2);
    k_bnprep<<<1, 128, 0, stream>>>(st2, g2, be2, bn2, 128, 1.0f / (float)MM);
    k_pool<<<dim3(NN / 256, BB), 256, 0, stream>>>(h2b, bn2, psum, pmax);
    k_attn<<<1, 1024, 0, stream>>>(psum, pmax, fa1, fa2, bn2, sa, sb);
    k_final<<<(MM * H2 / 8) / 256, 256, 0, stream>>>(h2b, sa, sb, out);
}

// Round 10
// 382.834 us; speedup vs baseline: 1.0972x; 1.0151x over previous
//
#include <hip/hip_runtime.h>
#include <math.h>

// Problem constants (fixed by setup_inputs)
constexpr int BB = 8;
constexpr int NN = 16384;
constexpr int SS = 2048;
constexpr int D2 = 256;
constexpr int H1 = 256;
constexpr int H2 = 128;
constexpr int MM = BB * NN;   // 131072 rows
constexpr int LDB = 40;       // LDS leading dim (bf16 elems): 80 B, 16B-aligned

typedef __attribute__((ext_vector_type(8))) short short8;    // bf16x8 frag (4 VGPRs)
typedef __attribute__((ext_vector_type(16))) float f32x16;   // 32x32 accumulator

__device__ __forceinline__ unsigned short f2b(float f) {     // fp32 -> bf16 RNE
    union { float f; unsigned u; } v; v.f = f;
    unsigned r = v.u + 0x7FFFu + ((v.u >> 16) & 1u);
    return (unsigned short)(r >> 16);
}
__device__ __forceinline__ unsigned pk2(float lo, float hi) {
    return (unsigned)f2b(lo) | ((unsigned)f2b(hi) << 16);
}
__device__ __forceinline__ float b2f_lo(unsigned p) { return __uint_as_float(p << 16); }
__device__ __forceinline__ float b2f_hi(unsigned p) { return __uint_as_float(p & 0xFFFF0000u); }

__device__ __forceinline__ unsigned umed3(unsigned a, unsigned b, unsigned c) {
    unsigned d; asm("v_med3_u32 %0, %1, %2, %3" : "=v"(d) : "v"(a), "v"(b), "v"(c)); return d;
}

// ---------------------------------------------------------------- init
__global__ void k_init(float* __restrict__ st1, float* __restrict__ st2,
                       float* __restrict__ psum, int* __restrict__ pmax) {
    int t = threadIdx.x;
    if (t < 512) st1[t] = 0.f;
    if (t < 256) st2[t] = 0.f;
    if (t < 1024) { psum[t] = 0.f; pmax[t] = 0; }
}

// ---------------------------------------------------------------- weight fp32->bf16 prep
__global__ void k_wprep(const float* __restrict__ w1, const float* __restrict__ w2,
                        unsigned short* __restrict__ w1b, unsigned short* __restrict__ w2b) {
    int i = blockIdx.x * 256 + threadIdx.x;
    if (i < H1 * 384) w1b[i] = f2b(w1[i]);
    if (i < H2 * 256) w2b[i] = f2b(w2[i]);
}

// ---------------------------------------------------------------- xyz2 -> float4 pack (for scalar loads)
__global__ void k_xyzprep(const float* __restrict__ xyz2, float4* __restrict__ xyz2p) {
    int i = blockIdx.x * 256 + threadIdx.x;   // 0 .. BB*SS-1
    if (i < BB * SS) {
        xyz2p[i] = make_float4(xyz2[i * 3], xyz2[i * 3 + 1], xyz2[i * 3 + 2], 0.f);
    }
}

// ---------------------------------------------------------------- 3-NN
// Wave-uniform float4 candidate stream; top-4 insert via {min, med3, med3, med3}.
__global__ __launch_bounds__(256) void k_knn(const float* __restrict__ xyz1,
                                             const float4* __restrict__ xyz2p,
                                             int* __restrict__ idx,
                                             float* __restrict__ wgt) {
    __shared__ unsigned cand[64][16];             // 4 KB: [query][chunk*4+t]
    const int b = blockIdx.y;
    const int tid = threadIdx.x;
    const int ql = tid & 63;                      // query-local
    const int n = blockIdx.x * 64 + ql;

    const float* q = xyz1 + ((size_t)b * NN + n) * 3;
    const float qx = q[0], qy = q[1], qz = q[2];

    // wave-uniform chunk base -> scalar loads through K$
    const int chunk = __builtin_amdgcn_readfirstlane(tid >> 6);   // 0..3
    const float4* cp = xyz2p + ((size_t)b << 11) + (chunk << 9);

    unsigned k0 = 0xFFFFFFFFu, k1 = 0xFFFFFFFFu, k2 = 0xFFFFFFFFu, k3 = 0xFFFFFFFFu;
#pragma unroll 4
    for (int j = 0; j < 512; ++j) {
        const float4 p = cp[j];
        const float dx = qx - p.x;
        const float dy = qy - p.y;
        const float dz = qz - p.z;
        const float d = fmaf(dx, dx, fmaf(dy, dy, dz * dz));
        const unsigned key = (__float_as_uint(d) & 0xFFFFFE00u) | (unsigned)j;
        // sorted top-4 insert: {min, med3, med3, med3} (4 independent ops)
        const unsigned n0 = min(k0, key);
        const unsigned n1 = umed3(k0, k1, key);
        const unsigned n2 = umed3(k1, k2, key);
        const unsigned n3 = umed3(k2, k3, key);
        k0 = n0; k1 = n1; k2 = n2; k3 = n3;
    }
    unsigned* cq = cand[ql] + chunk * 4;
    cq[0] = k0; cq[1] = k1; cq[2] = k2; cq[3] = k3;
    __syncthreads();

    if (tid < 64) {
        const double qxd = (double)qx, qyd = (double)qy, qzd = (double)qz;
        double t0 = 1e300, t1 = 1e300, t2 = 1e300;
        int i0 = 0, i1 = 0, i2 = 0;
#pragma unroll
        for (int c = 0; c < 16; ++c) {
            const int s = ((c >> 2) << 9) + (int)(cand[tid][c] & 0x1FFu);
            const float4 p = xyz2p[((size_t)b << 11) + s];
            const double dx = qxd - (double)p.x;
            const double dy = qyd - (double)p.y;
            const double dz = qzd - (double)p.z;
            const double d = fma(dx, dx, fma(dy, dy, dz * dz));
            if (d < t2) {
                if (d < t0)      { t2 = t1; i2 = i1; t1 = t0; i1 = i0; t0 = d; i0 = s; }
                else if (d < t1) { t2 = t1; i2 = i1; t1 = d; i1 = s; }
                else             { t2 = d; i2 = s; }
            }
        }
        const double r0 = 1.0 / (t0 + 1e-8);
        const double r1 = 1.0 / (t1 + 1e-8);
        const double r2 = 1.0 / (t2 + 1e-8);
        const double inv = 1.0 / (r0 + r1 + r2);
        const size_t o = ((size_t)b * NN + n) * 3;
        idx[o + 0] = i0; idx[o + 1] = i1; idx[o + 2] = i2;
        wgt[o + 0] = (float)(r0 * inv);
        wgt[o + 1] = (float)(r1 * inv);
        wgt[o + 2] = (float)(r2 * inv);
    }
}

// ---------------------------------------------------------------- Z-prep: Z = p2 x W1tail^T
// XCD-aligned: block d -> XCD d%8 (HW round-robin), batch = d&7, so batch b's
// Z slice is produced (and likely cached) on XCD b.
__global__ __launch_bounds__(256) void k_zprep(const float* __restrict__ p2,
                                               const unsigned short* __restrict__ w1b,
                                               float* __restrict__ Z) {
    __shared__ __align__(16) unsigned short As[64 * LDB];    // 5 KB
    __shared__ __align__(16) unsigned short Bs[256 * LDB];   // 20 KB
    const int tid = threadIdx.x;
    const int bid = blockIdx.x;                   // 256 = 8 batches x 32
    const int s0 = ((bid & 7) << 11) + ((bid >> 3) << 6);
    const int wave = tid >> 6, lane = tid & 63;
    const int ln = lane & 31, hk = lane >> 5;
    const int wn = wave << 6;                 // wave-tile 64 rows x 64 cols
    const int r = tid >> 2, q = tid & 3;

    f32x16 acc[2][2];
#pragma unroll
    for (int mt = 0; mt < 2; ++mt)
#pragma unroll
        for (int nt = 0; nt < 2; ++nt)
#pragma unroll
            for (int e = 0; e < 16; ++e) acc[mt][nt][e] = 0.f;

    float4 ra[2];
    uint4 rb[4];
    auto prefetch = [&](int kc) {
        const unsigned short* bsrc = w1b + (size_t)tid * 384 + 128 + kc * 32;
        rb[0] = *(const uint4*)(bsrc);
        rb[1] = *(const uint4*)(bsrc + 8);
        rb[2] = *(const uint4*)(bsrc + 16);
        rb[3] = *(const uint4*)(bsrc + 24);
        const float* asrc = p2 + (((size_t)(s0 + r)) << 8) + kc * 32 + q * 8;
        ra[0] = *(const float4*)(asrc);
        ra[1] = *(const float4*)(asrc + 4);
    };

    prefetch(0);

    for (int kc = 0; kc < 8; ++kc) {
        const uint4 pa = make_uint4(pk2(ra[0].x, ra[0].y), pk2(ra[0].z, ra[0].w),
                                    pk2(ra[1].x, ra[1].y), pk2(ra[1].z, ra[1].w));
        const uint4 b0 = rb[0], b1 = rb[1], b2 = rb[2], b3 = rb[3];

        __syncthreads();
        *(uint4*)&As[r * LDB + q * 8] = pa;
        *(uint4*)&Bs[tid * LDB + 0]  = b0;
        *(uint4*)&Bs[tid * LDB + 8]  = b1;
        *(uint4*)&Bs[tid * LDB + 16] = b2;
        *(uint4*)&Bs[tid * LDB + 24] = b3;
        __syncthreads();

        if (kc < 7) prefetch(kc + 1);

        short8 af[2][2], bfv[2][2];
#pragma unroll
        for (int mt = 0; mt < 2; ++mt)
#pragma unroll
            for (int ks = 0; ks < 2; ++ks)
                af[mt][ks] = *(const short8*)&As[(mt * 32 + ln) * LDB + ks * 16 + hk * 8];
#pragma unroll
        for (int nt = 0; nt < 2; ++nt)
#pragma unroll
            for (int ks = 0; ks < 2; ++ks)
                bfv[nt][ks] = *(const short8*)&Bs[(wn + nt * 32 + ln) * LDB + ks * 16 + hk * 8];
#pragma unroll
        for (int mt = 0; mt < 2; ++mt)
#pragma unroll
            for (int nt = 0; nt < 2; ++nt)
#pragma unroll
                for (int ks = 0; ks < 2; ++ks)
                    acc[mt][nt] = __builtin_amdgcn_mfma_f32_32x32x16_bf16(
                        af[mt][ks], bfv[nt][ks], acc[mt][nt], 0, 0, 0);
    }

#pragma unroll
    for (int mt = 0; mt < 2; ++mt)
#pragma unroll
        for (int nt = 0; nt < 2; ++nt)
#pragma unroll
            for (int e = 0; e < 16; ++e) {
                const int rl = mt * 32 + (e & 3) + ((e >> 2) << 3) + (hk << 2);
                Z[(((size_t)(s0 + rl)) << 8) + wn + nt * 32 + ln] = acc[mt][nt][e];
            }
}

// ---------------------------------------------------------------- GEMM1:
// h1 = p1 x W1head^T (K=128 streaming) + epilogue interp-gather from Z.
// Epilogue v6: 2-deep software pipeline over 16 two-row batches — issue
// batch i+1's 12 gather loads before computing batch i (counted vmcnt).
// launch_bounds(256,3): room for the double buffer without spill.
__global__ __launch_bounds__(256, 3) void k_gemm1(const float* __restrict__ p1,
                                                  const int* __restrict__ idx,
                                                  const float* __restrict__ wgt,
                                                  const unsigned short* __restrict__ w1b,
                                                  const float* __restrict__ b1p,
                                                  const float* __restrict__ Z,
                                                  unsigned short* __restrict__ h1b,
                                                  float* __restrict__ st1) {
    __shared__ __align__(16) unsigned short As[64 * LDB];    // 5 KB
    __shared__ __align__(16) unsigned short Bs[256 * LDB];   // 20 KB
    __shared__ float sSum[256], sSq[256];
    __shared__ __align__(16) unsigned sJW[64][8];            // {j0<<8, j1<<8, j2<<8, wa, wb, wc, -, -}

    const int tid = threadIdx.x;
    const int bid = blockIdx.x;                    // 2048 = 8 batches x 256
    const int b = bid & 7;                         // batch == XCD (d%8 round-robin)
    const int row0 = (b << 14) + ((bid >> 3) << 6);

    sSum[tid] = 0.f; sSq[tid] = 0.f;
    if (tid < 64) {
        const size_t o3 = (size_t)(row0 + tid) * 3;
        sJW[tid][0] = ((unsigned)idx[o3])     << 8;
        sJW[tid][1] = ((unsigned)idx[o3 + 1]) << 8;
        sJW[tid][2] = ((unsigned)idx[o3 + 2]) << 8;
        sJW[tid][3] = __float_as_uint(wgt[o3]);
        sJW[tid][4] = __float_as_uint(wgt[o3 + 1]);
        sJW[tid][5] = __float_as_uint(wgt[o3 + 2]);
    }

    const int wave = tid >> 6, lane = tid & 63;
    const int ln = lane & 31, hk = lane >> 5;
    const int wn = wave << 6;                 // wave-tile 64 rows x 64 cols
    const int r = tid >> 2, q = tid & 3;

    f32x16 acc[2][2];
#pragma unroll
    for (int mt = 0; mt < 2; ++mt)
#pragma unroll
        for (int nt = 0; nt < 2; ++nt)
#pragma unroll
            for (int e = 0; e < 16; ++e) acc[mt][nt][e] = 0.f;

    float4 ra[2];
    uint4 rb[4];
    auto prefetch = [&](int kc) {
        const unsigned short* bsrc = w1b + (size_t)tid * 384 + kc * 32;   // head cols 0..127
        rb[0] = *(const uint4*)(bsrc);
        rb[1] = *(const uint4*)(bsrc + 8);
        rb[2] = *(const uint4*)(bsrc + 16);
        rb[3] = *(const uint4*)(bsrc + 24);
        const float* asrc = p1 + (((size_t)(row0 + r)) << 7) + kc * 32 + q * 8;
        ra[0] = *(const float4*)(asrc);
        ra[1] = *(const float4*)(asrc + 4);
    };

    prefetch(0);

    for (int kc = 0; kc < 4; ++kc) {
        const uint4 pa = make_uint4(pk2(ra[0].x, ra[0].y), pk2(ra[0].z, ra[0].w),
                                    pk2(ra[1].x, ra[1].y), pk2(ra[1].z, ra[1].w));
        const uint4 b0 = rb[0], b1 = rb[1], b2 = rb[2], b3 = rb[3];

        __syncthreads();   // WAR: prior iteration's frag reads complete (also covers sJW write)
        *(uint4*)&As[r * LDB + q * 8] = pa;
        *(uint4*)&Bs[tid * LDB + 0]  = b0;
        *(uint4*)&Bs[tid * LDB + 8]  = b1;
        *(uint4*)&Bs[tid * LDB + 16] = b2;
        *(uint4*)&Bs[tid * LDB + 24] = b3;
        __syncthreads();

        if (kc < 3) prefetch(kc + 1);

        short8 af[2][2], bfv[2][2];
#pragma unroll
        for (int mt = 0; mt < 2; ++mt)
#pragma unroll
            for (int ks = 0; ks < 2; ++ks)
                af[mt][ks] = *(const short8*)&As[(mt * 32 + ln) * LDB + ks * 16 + hk * 8];
#pragma unroll
        for (int nt = 0; nt < 2; ++nt)
#pragma unroll
            for (int ks = 0; ks < 2; ++ks)
                bfv[nt][ks] = *(const short8*)&Bs[(wn + nt * 32 + ln) * LDB + ks * 16 + hk * 8];
#pragma unroll
        for (int mt = 0; mt < 2; ++mt)
#pragma unroll
            for (int nt = 0; nt < 2; ++nt)
#pragma unroll
                for (int ks = 0; ks < 2; ++ks)
                    acc[mt][nt] = __builtin_amdgcn_mfma_f32_32x32x16_bf16(
                        af[mt][ks], bfv[nt][ks], acc[mt][nt], 0, 0, 0);
    }

    // ---- epilogue v6: 16 two-row batches, 2-deep load/compute pipeline.
    //      Batch bi: rbase = (bi>>3)*32 + ((bi>>1)&3)*8 + hk*4 + (bi&1)*2,
    //      e0 = ((bi>>1)&3)*4 + (bi&1)*2. Same order as v5 -> bitwise-same output.
    const float* Zb = Z + ((size_t)b << 19);   // b * 2048 * 256
    const int c0 = wn + ln;
    const float bias0 = b1p[c0];
    const float bias1 = b1p[c0 + 32];
    float ps0 = 0.f, pq0 = 0.f, ps1 = 0.f, pq1 = 0.f;

    float zaA[2][6], zaB[2][6];

    auto LOADA = [&](int bi) {
        const int rb2 = ((bi >> 3) << 5) + (((bi >> 1) & 3) << 3) + (hk << 2) + ((bi & 1) << 1);
        const uint4 m0 = *(const uint4*)&sJW[rb2][0];
        const uint4 m1 = *(const uint4*)&sJW[rb2 + 1][0];
        const float* p00 = Zb + m0.x + c0;
        const float* p01 = Zb + m0.y + c0;
        const float* p02 = Zb + m0.z + c0;
        zaA[0][0] = p00[0];  zaA[0][1] = p00[32];
        zaA[0][2] = p01[0];  zaA[0][3] = p01[32];
        zaA[0][4] = p02[0];  zaA[0][5] = p02[32];
        const float* p10 = Zb + m1.x + c0;
        const float* p11 = Zb + m1.y + c0;
        const float* p12 = Zb + m1.z + c0;
        zaA[1][0] = p10[0];  zaA[1][1] = p10[32];
        zaA[1][2] = p11[0];  zaA[1][3] = p11[32];
        zaA[1][4] = p12[0];  zaA[1][5] = p12[32];
    };
    auto LOADB = [&](int bi) {
        const int rb2 = ((bi >> 3) << 5) + (((bi >> 1) & 3) << 3) + (hk << 2) + ((bi & 1) << 1);
        const uint4 m0 = *(const uint4*)&sJW[rb2][0];
        const uint4 m1 = *(const uint4*)&sJW[rb2 + 1][0];
        const float* p00 = Zb + m0.x + c0;
        const float* p01 = Zb + m0.y + c0;
        const float* p02 = Zb + m0.z + c0;
        zaB[0][0] = p00[0];  zaB[0][1] = p00[32];
        zaB[0][2] = p01[0];  zaB[0][3] = p01[32];
        zaB[0][4] = p02[0];  zaB[0][5] = p02[32];
        const float* p10 = Zb + m1.x + c0;
        const float* p11 = Zb + m1.y + c0;
        const float* p12 = Zb + m1.z + c0;
        zaB[1][0] = p10[0];  zaB[1][1] = p10[32];
        zaB[1][2] = p11[0];  zaB[1][3] = p11[32];
        zaB[1][4] = p12[0];  zaB[1][5] = p12[32];
    };
    auto COMPA = [&](int bi) {
        const int rb2 = ((bi >> 3) << 5) + (((bi >> 1) & 3) << 3) + (hk << 2) + ((bi & 1) << 1);
        const int mt = bi >> 3;
        const int e0 = (((bi >> 1) & 3) << 2) + ((bi & 1) << 1);
        const uint2 wxa = *(const uint2*)&sJW[rb2][2];        // [2]=j2 (dead), [3]=wa
        const uint2 wya = *(const uint2*)&sJW[rb2][4];        // [4]=wb, [5]=wc
        const uint2 wxb = *(const uint2*)&sJW[rb2 + 1][2];
        const uint2 wyb = *(const uint2*)&sJW[rb2 + 1][4];
        const float wA0 = __uint_as_float(wxa.y), wB0 = __uint_as_float(wya.x), wC0 = __uint_as_float(wya.y);
        const float wA1 = __uint_as_float(wxb.y), wB1 = __uint_as_float(wyb.x), wC1 = __uint_as_float(wyb.y);
        {
            const float v0 = fmaf(wA0, zaA[0][0], fmaf(wB0, zaA[0][2], wC0 * zaA[0][4]));
            const float v1 = fmaf(wA0, zaA[0][1], fmaf(wB0, zaA[0][3], wC0 * zaA[0][5]));
            const float o0 = acc[mt][0][e0] + bias0 + v0;
            const float o1 = acc[mt][1][e0] + bias1 + v1;
            ps0 += o0; pq0 = fmaf(o0, o0, pq0);
            ps1 += o1; pq1 = fmaf(o1, o1, pq1);
            const size_t ro = ((size_t)(row0 + rb2)) << 8;
            h1b[ro + c0]      = f2b(o0);
            h1b[ro + c0 + 32] = f2b(o1);
        }
        {
            const float v0 = fmaf(wA1, zaA[1][0], fmaf(wB1, zaA[1][2], wC1 * zaA[1][4]));
            const float v1 = fmaf(wA1, zaA[1][1], fmaf(wB1, zaA[1][3], wC1 * zaA[1][5]));
            const float o0 = acc[mt][0][e0 + 1] + bias0 + v0;
            const float o1 = acc[mt][1][e0 + 1] + bias1 + v1;
            ps0 += o0; pq0 = fmaf(o0, o0, pq0);
            ps1 += o1; pq1 = fmaf(o1, o1, pq1);
            const size_t ro = ((size_t)(row0 + rb2 + 1)) << 8;
            h1b[ro + c0]      = f2b(o0);
            h1b[ro + c0 + 32] = f2b(o1);
        }
    };
    auto COMPB = [&](int bi) {
        const int rb2 = ((bi >> 3) << 5) + (((bi >> 1) & 3) << 3) + (hk << 2) + ((bi & 1) << 1);
        const int mt = bi >> 3;
        const int e0 = (((bi >> 1) & 3) << 2) + ((bi & 1) << 1);
        const uint2 wxa = *(const uint2*)&sJW[rb2][2];
        const uint2 wya = *(const uint2*)&sJW[rb2][4];
        const uint2 wxb = *(const uint2*)&sJW[rb2 + 1][2];
        const uint2 wyb = *(const uint2*)&sJW[rb2 + 1][4];
        const float wA0 = __uint_as_float(wxa.y), wB0 = __uint_as_float(wya.x), wC0 = __uint_as_float(wya.y);
        const float wA1 = __uint_as_float(wxb.y), wB1 = __uint_as_float(wyb.x), wC1 = __uint_as_float(wyb.y);
        {
            const float v0 = fmaf(wA0, zaB[0][0], fmaf(wB0, zaB[0][2], wC0 * zaB[0][4]));
            const float v1 = fmaf(wA0, zaB[0][1], fmaf(wB0, zaB[0][3], wC0 * zaB[0][5]));
            const float o0 = acc[mt][0][e0] + bias0 + v0;
            const float o1 = acc[mt][1][e0] + bias1 + v1;
            ps0 += o0; pq0 = fmaf(o0, o0, pq0);
            ps1 += o1; pq1 = fmaf(o1, o1, pq1);
            const size_t ro = ((size_t)(row0 + rb2)) << 8;
            h1b[ro + c0]      = f2b(o0);
            h1b[ro + c0 + 32] = f2b(o1);
        }
        {
            const float v0 = fmaf(wA1, zaB[1][0], fmaf(wB1, zaB[1][2], wC1 * zaB[1][4]));
            const float v1 = fmaf(wA1, zaB[1][1], fmaf(wB1, zaB[1][3], wC1 * zaB[1][5]));
            const float o0 = acc[mt][0][e0 + 1] + bias0 + v0;
            const float o1 = acc[mt][1][e0 + 1] + bias1 + v1;
            ps0 += o0; pq0 = fmaf(o0, o0, pq0);
            ps1 += o1; pq1 = fmaf(o1, o1, pq1);
            const size_t ro = ((size_t)(row0 + rb2 + 1)) << 8;
            h1b[ro + c0]      = f2b(o0);
            h1b[ro + c0 + 32] = f2b(o1);
        }
    };

    LOADA(0);
#pragma unroll
    for (int bp = 0; bp < 8; ++bp) {
        LOADB(2 * bp + 1);          // issue next batch's loads
        COMPA(2 * bp);              // waits only on zaA (vmcnt counted)
        if (bp < 7) LOADA(2 * bp + 2);
        COMPB(2 * bp + 1);
    }

    atomicAdd(&sSum[c0], ps0);      atomicAdd(&sSq[c0], pq0);
    atomicAdd(&sSum[c0 + 32], ps1); atomicAdd(&sSq[c0 + 32], pq1);
    __syncthreads();
    atomicAdd(&st1[tid], sSum[tid]);
    atomicAdd(&st1[256 + tid], sSq[tid]);
}

// ---------------------------------------------------------------- BN coef prep
__global__ void k_bnprep(const float* __restrict__ st, const float* __restrict__ g,
                         const float* __restrict__ be, float* __restrict__ bn,
                         int C, float invM) {
    int c = blockIdx.x * blockDim.x + threadIdx.x;
    if (c < C) {
        float mean = st[c] * invM;
        float var = st[C + c] * invM - mean * mean;
        float a = g[c] / sqrtf(var + 1e-5f);
        bn[c] = a;
        bn[C + c] = fmaf(-mean, a, be[c]);
    }
}

// ---------------------------------------------------------------- GEMM2: MFMA bf16, BN1+ReLU fused,
// register-prefetch pipeline, bf16 in/out, stats2
__global__ __launch_bounds__(256) void k_gemm2(const unsigned short* __restrict__ h1b,
                                               const unsigned short* __restrict__ w2b,
                                               const float* __restrict__ b2p,
                                               const float* __restrict__ bn1,
                                               unsigned short* __restrict__ h2b,
                                               float* __restrict__ st2) {
    __shared__ __align__(16) unsigned short As[128 * LDB];
    __shared__ __align__(16) unsigned short Bs[128 * LDB];
    __shared__ float sBNa[256], sBNb[256];
    __shared__ float sSum[128], sSq[128];

    const int tid = threadIdx.x;
    const int row0 = blockIdx.x * 128;

    sBNa[tid] = bn1[tid];
    sBNb[tid] = bn1[256 + tid];
    if (tid < 128) { sSum[tid] = 0.f; sSq[tid] = 0.f; }

    const int wave = tid >> 6, lane = tid & 63;
    const int ln = lane & 31, hk = lane >> 5;
    const int wm = (wave & 1) << 6, wn = (wave >> 1) << 6;
    const int r = tid >> 1, half = tid & 1;

    f32x16 acc[2][2];
#pragma unroll
    for (int mt = 0; mt < 2; ++mt)
#pragma unroll
        for (int nt = 0; nt < 2; ++nt)
#pragma unroll
            for (int e = 0; e < 16; ++e) acc[mt][nt][e] = 0.f;

    uint4 rA0, rA1, rB0, rB1;
    auto prefetch = [&](int kc) {
        const unsigned short* asrc = h1b + (size_t)(row0 + r) * 256 + kc * 32 + half * 16;
        rA0 = *(const uint4*)asrc;
        rA1 = *(const uint4*)(asrc + 8);
        const unsigned short* bsrc = w2b + (size_t)r * 256 + kc * 32 + half * 16;
        rB0 = *(const uint4*)bsrc;
        rB1 = *(const uint4*)(bsrc + 8);
    };

    prefetch(0);
    __syncthreads();   // sBN visible

    for (int kc = 0; kc < 8; ++kc) {
        const int k0 = kc * 32 + half * 16;
        unsigned pw[8] = {rA0.x, rA0.y, rA0.z, rA0.w, rA1.x, rA1.y, rA1.z, rA1.w};
        unsigned po[8];
#pragma unroll
        for (int gi = 0; gi < 8; ++gi) {
            float lo = b2f_lo(pw[gi]);
            float hi = b2f_hi(pw[gi]);
            lo = fmaxf(fmaf(sBNa[k0 + 2 * gi], lo, sBNb[k0 + 2 * gi]), 0.f);
            hi = fmaxf(fmaf(sBNa[k0 + 2 * gi + 1], hi, sBNb[k0 + 2 * gi + 1]), 0.f);
            po[gi] = pk2(lo, hi);
        }
        const uint4 pa0 = make_uint4(po[0], po[1], po[2], po[3]);
        const uint4 pa1 = make_uint4(po[4], po[5], po[6], po[7]);
        const uint4 qb0 = rB0, qb1 = rB1;

        __syncthreads();
        *(uint4*)&As[r * LDB + half * 16] = pa0;
        *(uint4*)&As[r * LDB + half * 16 + 8] = pa1;
        *(uint4*)&Bs[r * LDB + half * 16] = qb0;
        *(uint4*)&Bs[r * LDB + half * 16 + 8] = qb1;
        __syncthreads();

        if (kc < 7) prefetch(kc + 1);

        short8 af[2][2], bfv[2][2];
#pragma unroll
        for (int mt = 0; mt < 2; ++mt)
#pragma unroll
            for (int ks = 0; ks < 2; ++ks)
                af[mt][ks] = *(const short8*)&As[(wm + mt * 32 + ln) * LDB + ks * 16 + hk * 8];
#pragma unroll
        for (int nt = 0; nt < 2; ++nt)
#pragma unroll
            for (int ks = 0; ks < 2; ++ks)
                bfv[nt][ks] = *(const short8*)&Bs[(wn + nt * 32 + ln) * LDB + ks * 16 + hk * 8];
#pragma unroll
        for (int mt = 0; mt < 2; ++mt)
#pragma unroll
            for (int nt = 0; nt < 2; ++nt)
#pragma unroll
                for (int ks = 0; ks < 2; ++ks)
                    acc[mt][nt] = __builtin_amdgcn_mfma_f32_32x32x16_bf16(
                        af[mt][ks], bfv[nt][ks], acc[mt][nt], 0, 0, 0);
    }

#pragma unroll
    for (int nt = 0; nt < 2; ++nt) {
        const int col = wn + nt * 32 + ln;
        const float bias = b2p[col];
        float ps = 0.f, pq = 0.f;
#pragma unroll
        for (int mt = 0; mt < 2; ++mt) {
#pragma unroll
            for (int e = 0; e < 16; ++e) {
                const int rl = wm + mt * 32 + (e & 3) + ((e >> 2) << 3) + (hk << 2);
                const float o = acc[mt][nt][e] + bias;
                ps += o;
                pq = fmaf(o, o, pq);
                h2b[(((size_t)(row0 + rl)) << 7) + col] = f2b(o);
            }
        }
        atomicAdd(&sSum[col], ps);
        atomicAdd(&sSq[col], pq);
    }
    __syncthreads();
    if (tid < 128) {
        atomicAdd(&st2[tid], sSum[tid]);
        atomicAdd(&st2[128 + tid], sSq[tid]);
    }
}

// ---------------------------------------------------------------- pool pass (bf16 h2)
__global__ __launch_bounds__(256) void k_pool(const unsigned short* __restrict__ h2b,
                                              const float* __restrict__ bn2,
                                              float* __restrict__ psum,
                                              int* __restrict__ pmax) {
    const int b = blockIdx.y;
    const int n0 = blockIdx.x * 256;
    const int tid = threadIdx.x;
    const int c = tid & 127, rh = tid >> 7;
    const float a = bn2[c], bc = bn2[128 + c];
    const unsigned short* base = h2b + (((size_t)b * NN + n0 + rh) << 7) + c;
    float s = 0.f, m = 0.f;
    for (int i = 0; i < 128; ++i) {
        float v = __uint_as_float((unsigned)base[(size_t)i * 256] << 16);
        float x = fmaxf(fmaf(a, v, bc), 0.f);
        s += x;
        m = fmaxf(m, x);
    }
    __shared__ float rs[256];
    __shared__ float rm[256];
    rs[tid] = s; rm[tid] = m;
    __syncthreads();
    if (tid < 128) {
        float ts = rs[tid] + rs[tid + 128];
        float tm = fmaxf(rm[tid], rm[tid + 128]);
        atomicAdd(&psum[b * 128 + c], ts);
        atomicMax(&pmax[b * 128 + c], __float_as_int(tm));
    }
}

// ---------------------------------------------------------------- SE attention
__global__ __launch_bounds__(1024) void k_attn(const float* __restrict__ psum,
                                               const int* __restrict__ pmax,
                                               const float* __restrict__ fa1,
                                               const float* __restrict__ fa2,
                                               const float* __restrict__ bn2,
                                               float* __restrict__ sa,
                                               float* __restrict__ sb) {
    __shared__ float tS[128];
    const int tid = threadIdx.x;
    if (tid < 128) {
        const int b = tid >> 4, j = tid & 15;
        float da = 0.f, dm = 0.f;
        for (int cc = 0; cc < 128; ++cc) {
            float f = fa1[j * 128 + cc];
            da = fmaf(psum[b * 128 + cc] * (1.0f / 16384.0f), f, da);
            dm = fmaf(__int_as_float(pmax[b * 128 + cc]), f, dm);
        }
        tS[tid] = fmaxf(da, 0.f) + fmaxf(dm, 0.f);
    }
    __syncthreads();
    const int b = tid >> 7, c = tid & 127;
    float s = 0.f;
#pragma unroll
    for (int j = 0; j < 16; ++j) s = fmaf(tS[b * 16 + j], fa2[c * 16 + j], s);
    const float sc = 1.f / (1.f + expf(-s));
    sa[b * 128 + c] = bn2[c] * sc;
    sb[b * 128 + c] = bn2[128 + c] * sc;
}

// ---------------------------------------------------------------- final (bf16 h2 -> fp32 out)
__global__ void k_final(const unsigned short* __restrict__ h2b, const float* __restrict__ sa,
                        const float* __restrict__ sb, float* __restrict__ out) {
    const size_t i = (size_t)blockIdx.x * blockDim.x + threadIdx.x;  // 8-elem group
    const int cg = (int)(i & 15) * 8;
    const size_t row = i >> 4;
    const int b = (int)(row >> 14);
    const uint4 h = *(const uint4*)(h2b + (row << 7) + cg);
    const float4 A0 = *(const float4*)&sa[b * 128 + cg];
    const float4 A1 = *(const float4*)&sa[b * 128 + cg + 4];
    const float4 B0 = *(const float4*)&sb[b * 128 + cg];
    const float4 B1 = *(const float4*)&sb[b * 128 + cg + 4];
    float4 o0, o1;
    o0.x = fmaxf(fmaf(A0.x, b2f_lo(h.x), B0.x), 0.f);
    o0.y = fmaxf(fmaf(A0.y, b2f_hi(h.x), B0.y), 0.f);
    o0.z = fmaxf(fmaf(A0.z, b2f_lo(h.y), B0.z), 0.f);
    o0.w = fmaxf(fmaf(A0.w, b2f_hi(h.y), B0.w), 0.f);
    o1.x = fmaxf(fmaf(A1.x, b2f_lo(h.z), B1.x), 0.f);
    o1.y = fmaxf(fmaf(A1.y, b2f_hi(h.z), B1.y), 0.f);
    o1.z = fmaxf(fmaf(A1.z, b2f_lo(h.w), B1.z), 0.f);
    o1.w = fmaxf(fmaf(A1.w, b2f_hi(h.w), B1.w), 0.f);
    *(float4*)(out + (row << 7) + cg) = o0;
    *(float4*)(out + (row << 7) + cg + 4) = o1;
}

// ---------------------------------------------------------------- launch
extern "C" void kernel_launch(void* const* d_in, const int* in_sizes, int n_in,
                              void* d_out, int out_size, void* d_ws, size_t ws_size,
                              hipStream_t stream) {
    const float* xyz1 = (const float*)d_in[0];
    const float* xyz2 = (const float*)d_in[1];
    const float* p1   = (const float*)d_in[2];
    const float* p2   = (const float*)d_in[3];
    const float* w1   = (const float*)d_in[4];
    const float* b1   = (const float*)d_in[5];
    const float* g1   = (const float*)d_in[6];
    const float* be1  = (const float*)d_in[7];
    const float* w2   = (const float*)d_in[8];
    const float* b2   = (const float*)d_in[9];
    const float* g2   = (const float*)d_in[10];
    const float* be2  = (const float*)d_in[11];
    const float* fa1  = (const float*)d_in[12];
    const float* fa2  = (const float*)d_in[13];
    float* out = (float*)d_out;

    char* ws = (char*)d_ws;
    int*   idx  = (int*)ws;                                   // 1.57 MB
    float* wgt  = (float*)(ws + 1572864);                     // 1.57 MB
    unsigned short* h1b = (unsigned short*)(ws + 3145728);    // 67 MB bf16   [ends 70254592]
    unsigned short* h2b = (unsigned short*)(ws + 70254592);   // 33.5 MB bf16 [ends 103809024]
    // Z aliases h2b: Z (16.8 MB) is consumed by k_gemm1 (reads) strictly BEFORE
    // k_gemm2 writes h2b over it (stream-serial). No overlap in lifetime.
    float* Zbuf = (float*)(ws + 70254592);                    // 16.8 MB fp32
    float* st1  = (float*)(ws + 103809024);                   // 512 f
    float* bn1  = st1 + 512;                                  // 512 f
    float* st2  = bn1 + 512;                                  // 256 f
    float* bn2  = st2 + 256;                                  // 256 f
    float* psum = bn2 + 256;                                  // 1024 f
    int*   pmax = (int*)(psum + 1024);                        // 1024 i
    float* sa   = (float*)(pmax + 1024);                      // 1024 f
    float* sb   = sa + 1024;                                  // 1024 f
    unsigned short* w1b = (unsigned short*)(sb + 1024);       // 98304 bf16  [ends 104028160]
    unsigned short* w2b = w1b + 98304;                        // 32768 bf16  [ends 104093696]
    float4* xyz2p = (float4*)(ws + 104857600);                // 256 KB @ 100 MiB

    k_init<<<1, 1024, 0, stream>>>(st1, st2, psum, pmax);
    k_wprep<<<(H1 * 384 + 255) / 256, 256, 0, stream>>>(w1, w2, w1b, w2b);
    k_xyzprep<<<(BB * SS + 255) / 256, 256, 0, stream>>>(xyz2, xyz2p);
    k_knn<<<dim3(NN / 64, BB), 256, 0, stream>>>(xyz1, xyz2p, idx, wgt);
    k_zprep<<<BB * SS / 64, 256, 0, stream>>>(p2, w1b, Zbuf);
    k_gemm1<<<MM / 64, 256, 0, stream>>>(p1, idx, wgt, w1b, b1, Zbuf, h1b, st1);
    k_bnprep<<<1, 256, 0, stream>>>(st1, g1, be1, bn1, 256, 1.0f / (float)MM);
    k_gemm2<<<MM / 128, 256, 0, stream>>>(h1b, w2b, b2, bn1, h2b, st2);
    k_bnprep<<<1, 128, 0, stream>>>(st2, g2, be2, bn2, 128, 1.0f / (float)MM);
    k_pool<<<dim3(NN / 256, BB), 256, 0, stream>>>(h2b, bn2, psum, pmax);
    k_attn<<<1, 1024, 0, stream>>>(psum, pmax, fa1, fa2, bn2, sa, sb);
    k_final<<<(MM * H2 / 8) / 256, 256, 0, stream>>>(h2b, sa, sb, out);
}